// Round 15
// baseline (2724.668 us; speedup 1.0000x reference)
//
#include <hip/hip_runtime.h>
#include <stdint.h>

#define Bn 4
#define Cn 256
#define Hn 128
#define Wn 128
#define Nn 16384
#define EPSn 1e-10f

typedef unsigned short u16;
typedef __attribute__((ext_vector_type(8))) short short8;
typedef __attribute__((ext_vector_type(4))) short short4v;
typedef __attribute__((ext_vector_type(4))) float f32x4;

#define GLOAD_LDS16(g, l)                                                        \
    __builtin_amdgcn_global_load_lds(                                            \
        (const __attribute__((address_space(1))) unsigned int*)(const void*)(g), \
        (__attribute__((address_space(3))) unsigned int*)(void*)(l), 16, 0, 0)

#define MFMA16(a, b, c) __builtin_amdgcn_mfma_f32_16x16x32_bf16(a, b, c, 0, 0, 0)

__device__ __forceinline__ float bf2f(u16 u) {
    union { float f; uint32_t i; } v; v.i = ((uint32_t)u) << 16; return v.f;
}
__device__ __forceinline__ u16 f2bf(float f) {
    union { float f; uint32_t i; } v; v.f = f;
    uint32_t r = v.i + 0x7FFFu + ((v.i >> 16) & 1u);
    return (u16)(r >> 16);
}
__device__ __forceinline__ float delu_f(float x) {
    return x >= 0.f ? fmaf(10.f, x, 1.f) : __expf(10.f * x);
}

// ---------------- prep: pack all weights into MFMA-fragment order ----------------
__global__ void prep_kernel(const float* __restrict__ wq1, const float* __restrict__ wk1,
                            const float* __restrict__ wv1,
                            const float* __restrict__ wq2, const float* __restrict__ wk2,
                            const float* __restrict__ wv2,
                            const float* __restrict__ wd1, const float* __restrict__ wd3,
                            const float* __restrict__ bd1, const float* __restrict__ bd3,
                            const float* __restrict__ gamma1, const float* __restrict__ gamma2,
                            u16* __restrict__ wq1p, u16* __restrict__ wk1p, u16* __restrict__ wv1p,
                            u16* __restrict__ wq2p, u16* __restrict__ wk2p, u16* __restrict__ wv2p,
                            u16* __restrict__ wallp1, u16* __restrict__ wallp2,
                            float* __restrict__ bfused)
{
    int idx = blockIdx.x * 256 + threadIdx.x;   // o*256 + c
    int o = idx >> 8, c = idx & 255;
    if (idx < 256) bfused[idx] = bd1[idx] + bd3[idx];
    int s = o >> 6, mf = (o >> 4) & 3, lr = o & 15;
    int kc = c >> 5, lk = (c >> 3) & 3, j = c & 7;
    int poff = ((kc * 4 + s) * 4 + mf) * 512 + (lk * 16 + lr) * 8 + j;
    wq1p[poff] = f2bf(wq1[idx]);
    wk1p[poff] = f2bf(wk1[idx]);
    wv1p[poff] = f2bf(wv1[idx]);
    wq2p[poff] = f2bf(wq2[idx]);
    wk2p[poff] = f2bf(wk2[idx]);
    wv2p[poff] = f2bf(wv2[idx]);
    float wd1v = wd1[idx];
    float inv1 = 1.f / gamma1[0];
    float inv2 = 1.f / gamma2[0];
    float diag = (o == c) ? 1.f : 0.f;
    #pragma unroll
    for (int tap = 0; tap < 9; ++tap) {
        float w = wd3[idx * 9 + tap] + (tap == 4 ? wd1v : 0.f);
        wallp1[tap * 65536 + poff] = f2bf(w + (tap == 4 ? diag * inv1 : 0.f));
        wallp2[tap * 65536 + poff] = f2bf(w + (tap == 4 ? diag * inv2 : 0.f));
    }
}

// ---------------- transpose (both images): x (B,C,N) f32 -> xT (B,N,C) bf16 ----------------
__global__ void transpose_kernel(const float* __restrict__ x1, const float* __restrict__ x2,
                                 u16* __restrict__ xT1, u16* __restrict__ xT2)
{
    __shared__ __align__(16) u16 tl[64][72];
    int t = threadIdx.x;
    int z = blockIdx.z, img = z >> 2, b = z & 3;
    const float* x = img ? x2 : x1;
    u16* xT = img ? xT2 : xT1;
    int n0 = blockIdx.x * 64, c0 = blockIdx.y * 64;
    int cl = t >> 4, nl = (t & 15) * 4;
    #pragma unroll
    for (int pc = 0; pc < 4; ++pc) {
        int c = pc * 16 + cl;
        float4 v = *(const float4*)&x[((size_t)(b * Cn + c0 + c)) * Nn + n0 + nl];
        tl[nl + 0][c] = f2bf(v.x);
        tl[nl + 1][c] = f2bf(v.y);
        tl[nl + 2][c] = f2bf(v.z);
        tl[nl + 3][c] = f2bf(v.w);
    }
    __syncthreads();
    #pragma unroll
    for (int ps = 0; ps < 2; ++ps) {
        int id = ps * 256 + t;
        int nr = id >> 3, cc = (id & 7) * 8;
        short8 v = *(const short8*)&tl[nr][cc];
        *(short8*)&xT[((size_t)(b * Nn + n0 + nr)) * 256 + c0 + cc] = v;
    }
}

// ---------------- qkv (R11 verbatim): single-shot B-tile, overlaid store bounce ----
#define OSTR 68
#define QK_LDS (2 * 128 * OSTR)        // 17408 u16 = 34816 B (Btile uses first 16384)

__global__ __launch_bounds__(256, 3) void qkv_kernel(
    const u16* __restrict__ xT1, const u16* __restrict__ xT2,
    const u16* __restrict__ wq1p, const u16* __restrict__ wk1p, const u16* __restrict__ wv1p,
    const u16* __restrict__ wq2p, const u16* __restrict__ wk2p, const u16* __restrict__ wv2p,
    const float* __restrict__ bq1, const float* __restrict__ bk1, const float* __restrict__ bv1,
    const float* __restrict__ bq2, const float* __restrict__ bk2, const float* __restrict__ bv2,
    u16* __restrict__ k1, u16* __restrict__ k2,
    u16* __restrict__ kv1, u16* __restrict__ kv2,
    float* __restrict__ qsum1, float* __restrict__ qsum2)
{
    __shared__ __align__(16) u16 lds[QK_LDS];
    int t = threadIdx.x;
    int nb = blockIdx.x, mb = blockIdx.y;
    int z = blockIdx.z, img = z >> 2, b = z & 3;
    const u16* xT  = img ? xT2  : xT1;
    const u16* wqp = img ? wq2p : wq1p;
    const u16* wkp = img ? wk2p : wk1p;
    const u16* wvp = img ? wv2p : wv1p;
    const float* bq = img ? bq2 : bq1;
    const float* bk = img ? bk2 : bk1;
    const float* bv = img ? bv2 : bv1;
    u16* kout  = img ? k2  : k1;
    u16* kvout = img ? kv2 : kv1;
    float* qsum = img ? qsum2 : qsum1;

    int n0 = nb * 64;
    int lane = t & 63, wid = t >> 6;
    int wm = wid >> 1, wn = wid & 1;
    int lr = lane & 15, lk = lane >> 4;
    int s = mb * 2 + wm;

    f32x4 zf = {0.f, 0.f, 0.f, 0.f};
    f32x4 accq[4][2], acck[4][2], accv[4][2];
    #pragma unroll
    for (int i = 0; i < 4; ++i)
        #pragma unroll
        for (int j = 0; j < 2; ++j) { accq[i][j] = zf; acck[i][j] = zf; accv[i][j] = zf; }

    int colp = lane >> 2, chp = (lane & 3) * 8;
    // stage the WHOLE B-tile: 8 loads/wave, all in flight at once
    #pragma unroll
    for (int kc = 0; kc < 8; ++kc) {
        const u16* g = xT + ((size_t)(b * Nn + n0 + wid * 16 + colp)) * 256 + kc * 32 + chp;
        GLOAD_LDS16(g, &lds[kc * 2048 + (wid * 16) * 32]);
    }
    __syncthreads();

    #pragma unroll
    for (int kc = 0; kc < 8; ++kc) {
        int abase = ((kc * 4 + s) * 4) * 512 + lane * 8;
        short8 bf0 = *(const short8*)&lds[kc * 2048 + (wn * 32 + 0 * 16 + lr) * 32 + lk * 8];
        short8 bf1 = *(const short8*)&lds[kc * 2048 + (wn * 32 + 1 * 16 + lr) * 32 + lk * 8];
        #pragma unroll
        for (int mf = 0; mf < 4; ++mf) {
            short8 aq = *(const short8*)&wqp[abase + mf * 512];
            short8 ak = *(const short8*)&wkp[abase + mf * 512];
            short8 av = *(const short8*)&wvp[abase + mf * 512];
            __builtin_amdgcn_s_setprio(1);
            accq[mf][0] = MFMA16(aq, bf0, accq[mf][0]);
            accq[mf][1] = MFMA16(aq, bf1, accq[mf][1]);
            acck[mf][0] = MFMA16(ak, bf0, acck[mf][0]);
            acck[mf][1] = MFMA16(ak, bf1, acck[mf][1]);
            accv[mf][0] = MFMA16(av, bf0, accv[mf][0]);
            accv[mf][1] = MFMA16(av, bf1, accv[mf][1]);
            __builtin_amdgcn_s_setprio(0);
        }
    }
    __syncthreads();                   // B-tile dead; lds becomes obuf

    // qsum: column sums of delu(q)
    float qs[2] = {0.f, 0.f};
    #pragma unroll
    for (int mf = 0; mf < 4; ++mf) {
        #pragma unroll
        for (int r = 0; r < 4; ++r) {
            int o = mb * 128 + wm * 64 + mf * 16 + lk * 4 + r;
            float bqv = bq[o];
            #pragma unroll
            for (int nf = 0; nf < 2; ++nf)
                qs[nf] += delu_f(accq[mf][nf][r] + bqv);
        }
    }
    #pragma unroll
    for (int nf = 0; nf < 2; ++nf) {
        float sgl = qs[nf];
        sgl += __shfl_xor(sgl, 16);
        sgl += __shfl_xor(sgl, 32);
        if (lk == 0)
            atomicAdd(&qsum[b * Nn + n0 + wn * 32 + nf * 16 + lr], sgl);
    }

    // write k and kv into padded obuf [2][128][OSTR]
    #pragma unroll
    for (int mf = 0; mf < 4; ++mf) {
        #pragma unroll
        for (int r = 0; r < 4; ++r) {
            int ol = wm * 64 + mf * 16 + lk * 4 + r;
            float bkv = bk[mb * 128 + ol];
            float bvv = bv[mb * 128 + ol];
            #pragma unroll
            for (int nf = 0; nf < 2; ++nf) {
                float kk = delu_f(acck[mf][nf][r] + bkv);
                float vv = accv[mf][nf][r] + bvv;
                int col = wn * 32 + nf * 16 + lr;
                lds[ol * OSTR + col] = f2bf(kk);
                lds[128 * OSTR + ol * OSTR + col] = f2bf(kk * vv);
            }
        }
    }
    __syncthreads();

    // vectorized stores: per instruction, 8 rows x 128B contiguous
    #pragma unroll
    for (int i = 0; i < 4; ++i) {
        int sid = i * 256 + t;
        int o = sid >> 3, seg = sid & 7;
        short8 v = *(const short8*)&lds[o * OSTR + seg * 8];
        *(short8*)&kout[((size_t)(b * Cn + mb * 128 + o)) * Nn + n0 + seg * 8] = v;
    }
    #pragma unroll
    for (int i = 0; i < 4; ++i) {
        int sid = i * 256 + t;
        int o = sid >> 3, seg = sid & 7;
        short8 v = *(const short8*)&lds[128 * OSTR + o * OSTR + seg * 8];
        *(short8*)&kvout[((size_t)(b * Cn + mb * 128 + o)) * Nn + n0 + seg * 8] = v;
    }
}

// ---------------- esum (both pairings): esum[b,c] = sum_n k[b,c,n] * qsum[b,n] ----------------
__global__ void esum_kernel(const u16* __restrict__ k1, const u16* __restrict__ k2,
                            const float* __restrict__ qsum1, const float* __restrict__ qsum2,
                            float* __restrict__ esum1, float* __restrict__ esum2)
{
    int c = blockIdx.x, b = blockIdx.y, pair = blockIdx.z, t = threadIdx.x;
    const u16* k = pair ? k1 : k2;            // esum1 <- k2 x qsum1 ; esum2 <- k1 x qsum2
    const float* qsum = pair ? qsum2 : qsum1;
    float* esum = pair ? esum2 : esum1;
    const u16* kr = k + ((size_t)(b * Cn + c)) * Nn;
    const float* qr = qsum + b * Nn;
    float s = 0.f;
    for (int i = t * 8; i < Nn; i += 2048) {
        short8 kv = *(const short8*)&kr[i];
        #pragma unroll
        for (int j = 0; j < 8; ++j) s = fmaf(bf2f((u16)kv[j]), qr[i + j], s);
    }
    #pragma unroll
    for (int m = 32; m; m >>= 1) s += __shfl_xor(s, m);
    __shared__ float red[4];
    if ((t & 63) == 0) red[t >> 6] = s;
    __syncthreads();
    if (t == 0) esum[b * Cn + c] = red[0] + red[1] + red[2] + red[3];
}

// ---------------- norm (both pairings): 1/(sum_c esum[b,c]*k[b,c,n] + eps) ----------------
__global__ void norm_kernel(const u16* __restrict__ k1, const u16* __restrict__ k2,
                            const float* __restrict__ esum1, const float* __restrict__ esum2,
                            float* __restrict__ norm1, float* __restrict__ norm2)
{
    __shared__ float es[256];
    int t = threadIdx.x, b = blockIdx.y, pair = blockIdx.z;
    const u16* k = pair ? k1 : k2;            // norm1 <- esum1,k2 ; norm2 <- esum2,k1
    const float* esum = pair ? esum2 : esum1;
    float* nrm = pair ? norm2 : norm1;
    es[t] = esum[b * Cn + t];
    __syncthreads();
    int n = blockIdx.x * 256 + t;
    const u16* kb = k + (size_t)b * Cn * Nn + n;
    float a = 0.f;
    #pragma unroll 8
    for (int c = 0; c < 256; ++c)
        a = fmaf(es[c], bf2f(kb[(size_t)c * Nn]), a);
    nrm[b * Nn + n] = 1.f / (a + EPSn);
}

// ---------------- pass 2: merged-image slab conv, single-buffered, 2 blocks/CU ------
// block: 128 och x 512 px (4 y-rows), 8 waves. halo [6][130][32] SINGLE buffer
// (49,920 B) -> 2 blocks/CU (one per image typically). grid 512 = both images.
// Cross-block wave overlap hides the per-chunk staging drain (1-block/CU couldn't).
#define BSZ6 (6 * 130 * 32)           // 24960 u16 per buffer

__global__ __launch_bounds__(512, 4) void conv_att_kernel(
    const u16* __restrict__ xT1, const u16* __restrict__ xT2,
    const u16* __restrict__ wallp1, const u16* __restrict__ wallp2,
    const float* __restrict__ bfused,
    const u16* __restrict__ kv1, const u16* __restrict__ kv2,
    const float* __restrict__ esum1, const float* __restrict__ esum2,
    const float* __restrict__ nrm1, const float* __restrict__ nrm2,
    const float* __restrict__ gamma1, const float* __restrict__ gamma2,
    float* __restrict__ out1, float* __restrict__ out2)
{
    __shared__ __align__(16) u16 Bl[BSZ6];   // 49,920 B single buffer
    int t = threadIdx.x;
    // 512 blocks; XCD = (img, b); slot sweeps (ys, mb) within the XCD
    int lin = (blockIdx.z * 32 + blockIdx.y) * 2 + blockIdx.x;
    int xcd = lin & 7, slot = lin >> 3;       // slot 0..63
    int img = xcd >> 2, b = xcd & 3;
    int ys = slot >> 1, mb = slot & 1;        // ys 0..31
    const u16* xT    = img ? xT2    : xT1;
    const u16* wallp = img ? wallp2 : wallp1;
    const u16* kv    = img ? kv2    : kv1;
    const float* esum = img ? esum2 : esum1;
    const float* nrm  = img ? nrm2  : nrm1;
    const float* gamma = img ? gamma2 : gamma1;
    float* out = img ? out2 : out1;

    int ybase = ys * 4;
    int lane = t & 63, wid = t >> 6;
    int wm = wid & 1, wy = wid >> 1;          // wm: och half, wy: y-row 0..3
    int lr = lane & 15, lk = lane >> 4;
    int s = mb * 2 + wm;

    f32x4 zf = {0.f, 0.f, 0.f, 0.f};
    f32x4 acc[4][8];
    #pragma unroll
    for (int i = 0; i < 4; ++i)
        #pragma unroll
        for (int j = 0; j < 8; ++j) acc[i][j] = zf;

    // zero x-pads (pos 0 and 129) for 6 rows, written once (staging never touches them)
    if (t < 48) {
        int row = t >> 3, pos = ((t >> 2) & 1) ? 129 : 0, q = t & 3;
        short8 z = {0, 0, 0, 0, 0, 0, 0, 0};
        *(short8*)&Bl[(row * 130 + pos) * 32 + q * 8] = z;
    }

    int colp = lane >> 2, chp = (lane & 3) * 8;
    auto STAGE = [&](int kc) {
        #pragma unroll
        for (int i = 0; i < 6; ++i) {
            int run = wid * 6 + i;        // 0..47 = hy(6) x seg(8)
            int hy = run >> 3, sx = run & 7;
            int yy = ybase + hy - 1;
            int dst = (hy * 130 + 1 + sx * 16) * 32;
            if (yy < 0 || yy >= Hn) {
                short8 z = {0, 0, 0, 0, 0, 0, 0, 0};
                *(short8*)&Bl[dst + lane * 8] = z;
            } else {
                const u16* g = xT + ((size_t)(b * Nn + yy * Wn + sx * 16 + colp)) * 256
                                  + kc * 32 + chp;
                GLOAD_LDS16(g, &Bl[dst]);
            }
        }
    };

    for (int kc = 0; kc < 8; ++kc) {
        int abase = ((kc * 4 + s) * 4) * 512 + lane * 8;
        // A-prefetch taps 0,1 (issued with staging; barrier drains both)
        short8 af[3][4];
        #pragma unroll
        for (int mf = 0; mf < 4; ++mf)
            af[0][mf] = *(const short8*)&wallp[0 * 65536 + abase + mf * 512];
        #pragma unroll
        for (int mf = 0; mf < 4; ++mf)
            af[1][mf] = *(const short8*)&wallp[1 * 65536 + abase + mf * 512];
        STAGE(kc);
        __syncthreads();                  // staging complete; other block hides this
        #pragma unroll
        for (int tap = 0; tap < 9; ++tap) {
            if (tap < 7) {
                #pragma unroll
                for (int mf = 0; mf < 4; ++mf)
                    af[(tap + 2) % 3][mf] =
                        *(const short8*)&wallp[(tap + 2) * 65536 + abase + mf * 512];
            }
            int dy = tap / 3, dx = tap % 3;
            short8 bf[8];
            #pragma unroll
            for (int nf = 0; nf < 8; ++nf)
                bf[nf] = *(const short8*)&Bl[((wy + dy) * 130 + nf * 16 + lr + dx) * 32 + lk * 8];
            __builtin_amdgcn_s_setprio(1);
            #pragma unroll
            for (int mf = 0; mf < 4; ++mf) {
                #pragma unroll
                for (int nf = 0; nf < 8; ++nf)
                    acc[mf][nf] = MFMA16(af[tap % 3][mf], bf[nf], acc[mf][nf]);
            }
            __builtin_amdgcn_s_setprio(0);
        }
        __syncthreads();                  // compute done before next chunk overwrites
    }

    float g = gamma[0];
    int y = ybase + wy;
    int nbase = y * Wn;
    float nr8[8];
    #pragma unroll
    for (int nf = 0; nf < 8; ++nf)
        nr8[nf] = nrm[b * Nn + nbase + nf * 16 + lr];
    #pragma unroll
    for (int mf = 0; mf < 4; ++mf) {
        #pragma unroll
        for (int r = 0; r < 4; ++r) {
            int o = mb * 128 + wm * 64 + mf * 16 + lk * 4 + r;
            float es_o = esum[b * Cn + o];
            float bf_o = bfused[o];
            size_t rowbase = ((size_t)(b * Cn + o)) * Nn + nbase;
            #pragma unroll
            for (int nf = 0; nf < 8; ++nf) {
                size_t idx = rowbase + nf * 16 + lr;
                float att = es_o * bf2f(kv[idx]) * nr8[nf];
                out[idx] = g * (acc[mf][nf][r] + bf_o + att);
            }
        }
    }
}

extern "C" void kernel_launch(void* const* d_in, const int* in_sizes, int n_in,
                              void* d_out, int out_size, void* d_ws, size_t ws_size,
                              hipStream_t stream)
{
    const float* x1  = (const float*)d_in[0];
    const float* x2  = (const float*)d_in[1];
    const float* wq1 = (const float*)d_in[2];
    const float* bq1 = (const float*)d_in[3];
    const float* wk1 = (const float*)d_in[4];
    const float* bk1 = (const float*)d_in[5];
    const float* wv1 = (const float*)d_in[6];
    const float* bv1 = (const float*)d_in[7];
    const float* wq2 = (const float*)d_in[8];
    const float* bq2 = (const float*)d_in[9];
    const float* wk2 = (const float*)d_in[10];
    const float* bk2 = (const float*)d_in[11];
    const float* wv2 = (const float*)d_in[12];
    const float* bv2 = (const float*)d_in[13];
    const float* wd1 = (const float*)d_in[14];
    const float* bd1 = (const float*)d_in[15];
    const float* wd3 = (const float*)d_in[16];
    const float* bd3 = (const float*)d_in[17];
    const float* gamma1 = (const float*)d_in[18];
    const float* gamma2 = (const float*)d_in[19];

    char* ws = (char*)d_ws;
    size_t off = 0;
    auto alloc = [&](size_t bytes) { char* p = ws + off; off += (bytes + 255) & ~(size_t)255; return p; };

    u16* xT1    = (u16*)alloc((size_t)Bn * Nn * Cn * 2);
    u16* xT2    = (u16*)alloc((size_t)Bn * Nn * Cn * 2);
    u16* k1     = (u16*)alloc((size_t)Bn * Cn * Nn * 2);
    u16* k2     = (u16*)alloc((size_t)Bn * Cn * Nn * 2);
    u16* kv2    = (u16*)alloc((size_t)Bn * Cn * Nn * 2);
    u16* wallp1 = (u16*)alloc((size_t)9 * 65536 * 2);
    u16* wallp2 = (u16*)alloc((size_t)9 * 65536 * 2);
    u16* wq1p   = (u16*)alloc(65536 * 2);
    u16* wk1p   = (u16*)alloc(65536 * 2);
    u16* wv1p   = (u16*)alloc(65536 * 2);
    u16* wq2p   = (u16*)alloc(65536 * 2);
    u16* wk2p   = (u16*)alloc(65536 * 2);
    u16* wv2p   = (u16*)alloc(65536 * 2);
    float* qsum1 = (float*)alloc(Bn * Nn * 4);
    float* qsum2 = (float*)alloc(Bn * Nn * 4);
    float* esum1 = (float*)alloc(Bn * Cn * 4);
    float* esum2 = (float*)alloc(Bn * Cn * 4);
    float* norm1 = (float*)alloc(Bn * Nn * 4);
    float* norm2 = (float*)alloc(Bn * Nn * 4);
    float* bfused = (float*)alloc(Cn * 4);

    float* out1 = (float*)d_out;
    float* out2 = out1 + (size_t)Bn * Cn * Nn;
    // kv1 parks in the out2 half of d_out; the merged conv kernel reads kv1 for img=0
    // blocks while img=1 blocks write out2 regions they own exclusively -- but kv1
    // overlaps out2, so kv1 must live elsewhere: use a dedicated ws buffer instead.
    u16* kv1 = (u16*)alloc((size_t)Bn * Cn * Nn * 2);

    hipMemsetAsync(qsum1, 0, Bn * Nn * 4, stream);
    hipMemsetAsync(qsum2, 0, Bn * Nn * 4, stream);

    prep_kernel<<<dim3(256), dim3(256), 0, stream>>>(wq1, wk1, wv1, wq2, wk2, wv2, wd1, wd3,
                                                     bd1, bd3, gamma1, gamma2,
                                                     wq1p, wk1p, wv1p, wq2p, wk2p, wv2p,
                                                     wallp1, wallp2, bfused);
    transpose_kernel<<<dim3(256, 4, 8), 256, 0, stream>>>(x1, x2, xT1, xT2);
    qkv_kernel<<<dim3(256, 2, 8), 256, 0, stream>>>(xT1, xT2,
                                                    wq1p, wk1p, wv1p, wq2p, wk2p, wv2p,
                                                    bq1, bk1, bv1, bq2, bk2, bv2,
                                                    k1, k2, kv1, kv2, qsum1, qsum2);
    esum_kernel<<<dim3(256, 4, 2), 256, 0, stream>>>(k1, k2, qsum1, qsum2, esum1, esum2);
    norm_kernel<<<dim3(64, 4, 2), 256, 0, stream>>>(k1, k2, esum1, esum2, norm1, norm2);
    conv_att_kernel<<<dim3(2, 32, 8), 512, 0, stream>>>(xT1, xT2, wallp1, wallp2, bfused,
                                                        kv1, kv2, esum1, esum2,
                                                        norm1, norm2, gamma1, gamma2,
                                                        out1, out2);
}

// Round 16
// 334.305 us; speedup vs baseline: 8.1502x; 8.1502x over previous
//
#include <hip/hip_runtime.h>
#include <stdint.h>

#define Bn 4
#define Cn 256
#define Hn 128
#define Wn 128
#define Nn 16384
#define EPSn 1e-10f

typedef unsigned short u16;
typedef __attribute__((ext_vector_type(8))) short short8;
typedef __attribute__((ext_vector_type(4))) short short4v;
typedef __attribute__((ext_vector_type(4))) float f32x4;

#define GLOAD_LDS16(g, l)                                                        \
    __builtin_amdgcn_global_load_lds(                                            \
        (const __attribute__((address_space(1))) unsigned int*)(const void*)(g), \
        (__attribute__((address_space(3))) unsigned int*)(void*)(l), 16, 0, 0)

#define MFMA16(a, b, c) __builtin_amdgcn_mfma_f32_16x16x32_bf16(a, b, c, 0, 0, 0)

__device__ __forceinline__ float bf2f(u16 u) {
    union { float f; uint32_t i; } v; v.i = ((uint32_t)u) << 16; return v.f;
}
__device__ __forceinline__ u16 f2bf(float f) {
    union { float f; uint32_t i; } v; v.f = f;
    uint32_t r = v.i + 0x7FFFu + ((v.i >> 16) & 1u);
    return (u16)(r >> 16);
}
__device__ __forceinline__ float delu_f(float x) {
    return x >= 0.f ? fmaf(10.f, x, 1.f) : __expf(10.f * x);
}

// ---------------- prep: pack all weights into MFMA-fragment order ----------------
__global__ void prep_kernel(const float* __restrict__ wq1, const float* __restrict__ wk1,
                            const float* __restrict__ wv1,
                            const float* __restrict__ wq2, const float* __restrict__ wk2,
                            const float* __restrict__ wv2,
                            const float* __restrict__ wd1, const float* __restrict__ wd3,
                            const float* __restrict__ bd1, const float* __restrict__ bd3,
                            const float* __restrict__ gamma1, const float* __restrict__ gamma2,
                            u16* __restrict__ wq1p, u16* __restrict__ wk1p, u16* __restrict__ wv1p,
                            u16* __restrict__ wq2p, u16* __restrict__ wk2p, u16* __restrict__ wv2p,
                            u16* __restrict__ wallp1, u16* __restrict__ wallp2,
                            float* __restrict__ bfused)
{
    int idx = blockIdx.x * 256 + threadIdx.x;   // o*256 + c
    int o = idx >> 8, c = idx & 255;
    if (idx < 256) bfused[idx] = bd1[idx] + bd3[idx];
    int s = o >> 6, mf = (o >> 4) & 3, lr = o & 15;
    int kc = c >> 5, lk = (c >> 3) & 3, j = c & 7;
    int poff = ((kc * 4 + s) * 4 + mf) * 512 + (lk * 16 + lr) * 8 + j;
    wq1p[poff] = f2bf(wq1[idx]);
    wk1p[poff] = f2bf(wk1[idx]);
    wv1p[poff] = f2bf(wv1[idx]);
    wq2p[poff] = f2bf(wq2[idx]);
    wk2p[poff] = f2bf(wk2[idx]);
    wv2p[poff] = f2bf(wv2[idx]);
    float wd1v = wd1[idx];
    float inv1 = 1.f / gamma1[0];
    float inv2 = 1.f / gamma2[0];
    float diag = (o == c) ? 1.f : 0.f;
    #pragma unroll
    for (int tap = 0; tap < 9; ++tap) {
        float w = wd3[idx * 9 + tap] + (tap == 4 ? wd1v : 0.f);
        wallp1[tap * 65536 + poff] = f2bf(w + (tap == 4 ? diag * inv1 : 0.f));
        wallp2[tap * 65536 + poff] = f2bf(w + (tap == 4 ? diag * inv2 : 0.f));
    }
}

// ---------------- transpose (both images): x (B,C,N) f32 -> xT (B,N,C) bf16 ----------------
__global__ void transpose_kernel(const float* __restrict__ x1, const float* __restrict__ x2,
                                 u16* __restrict__ xT1, u16* __restrict__ xT2)
{
    __shared__ __align__(16) u16 tl[64][72];
    int t = threadIdx.x;
    int z = blockIdx.z, img = z >> 2, b = z & 3;
    const float* x = img ? x2 : x1;
    u16* xT = img ? xT2 : xT1;
    int n0 = blockIdx.x * 64, c0 = blockIdx.y * 64;
    int cl = t >> 4, nl = (t & 15) * 4;
    #pragma unroll
    for (int pc = 0; pc < 4; ++pc) {
        int c = pc * 16 + cl;
        float4 v = *(const float4*)&x[((size_t)(b * Cn + c0 + c)) * Nn + n0 + nl];
        tl[nl + 0][c] = f2bf(v.x);
        tl[nl + 1][c] = f2bf(v.y);
        tl[nl + 2][c] = f2bf(v.z);
        tl[nl + 3][c] = f2bf(v.w);
    }
    __syncthreads();
    #pragma unroll
    for (int ps = 0; ps < 2; ++ps) {
        int id = ps * 256 + t;
        int nr = id >> 3, cc = (id & 7) * 8;
        short8 v = *(const short8*)&tl[nr][cc];
        *(short8*)&xT[((size_t)(b * Nn + n0 + nr)) * 256 + c0 + cc] = v;
    }
}

// ---------------- qkv (R11 verbatim): single-shot B-tile, overlaid store bounce ----
#define OSTR 68
#define QK_LDS (2 * 128 * OSTR)        // 17408 u16 = 34816 B (Btile uses first 16384)

__global__ __launch_bounds__(256, 3) void qkv_kernel(
    const u16* __restrict__ xT1, const u16* __restrict__ xT2,
    const u16* __restrict__ wq1p, const u16* __restrict__ wk1p, const u16* __restrict__ wv1p,
    const u16* __restrict__ wq2p, const u16* __restrict__ wk2p, const u16* __restrict__ wv2p,
    const float* __restrict__ bq1, const float* __restrict__ bk1, const float* __restrict__ bv1,
    const float* __restrict__ bq2, const float* __restrict__ bk2, const float* __restrict__ bv2,
    u16* __restrict__ k1, u16* __restrict__ k2,
    u16* __restrict__ kv1, u16* __restrict__ kv2,
    float* __restrict__ qsum1, float* __restrict__ qsum2)
{
    __shared__ __align__(16) u16 lds[QK_LDS];
    int t = threadIdx.x;
    int nb = blockIdx.x, mb = blockIdx.y;
    int z = blockIdx.z, img = z >> 2, b = z & 3;
    const u16* xT  = img ? xT2  : xT1;
    const u16* wqp = img ? wq2p : wq1p;
    const u16* wkp = img ? wk2p : wk1p;
    const u16* wvp = img ? wv2p : wv1p;
    const float* bq = img ? bq2 : bq1;
    const float* bk = img ? bk2 : bk1;
    const float* bv = img ? bv2 : bv1;
    u16* kout  = img ? k2  : k1;
    u16* kvout = img ? kv2 : kv1;
    float* qsum = img ? qsum2 : qsum1;

    int n0 = nb * 64;
    int lane = t & 63, wid = t >> 6;
    int wm = wid >> 1, wn = wid & 1;
    int lr = lane & 15, lk = lane >> 4;
    int s = mb * 2 + wm;

    f32x4 zf = {0.f, 0.f, 0.f, 0.f};
    f32x4 accq[4][2], acck[4][2], accv[4][2];
    #pragma unroll
    for (int i = 0; i < 4; ++i)
        #pragma unroll
        for (int j = 0; j < 2; ++j) { accq[i][j] = zf; acck[i][j] = zf; accv[i][j] = zf; }

    int colp = lane >> 2, chp = (lane & 3) * 8;
    // stage the WHOLE B-tile: 8 loads/wave, all in flight at once
    #pragma unroll
    for (int kc = 0; kc < 8; ++kc) {
        const u16* g = xT + ((size_t)(b * Nn + n0 + wid * 16 + colp)) * 256 + kc * 32 + chp;
        GLOAD_LDS16(g, &lds[kc * 2048 + (wid * 16) * 32]);
    }
    __syncthreads();

    #pragma unroll
    for (int kc = 0; kc < 8; ++kc) {
        int abase = ((kc * 4 + s) * 4) * 512 + lane * 8;
        short8 bf0 = *(const short8*)&lds[kc * 2048 + (wn * 32 + 0 * 16 + lr) * 32 + lk * 8];
        short8 bf1 = *(const short8*)&lds[kc * 2048 + (wn * 32 + 1 * 16 + lr) * 32 + lk * 8];
        #pragma unroll
        for (int mf = 0; mf < 4; ++mf) {
            short8 aq = *(const short8*)&wqp[abase + mf * 512];
            short8 ak = *(const short8*)&wkp[abase + mf * 512];
            short8 av = *(const short8*)&wvp[abase + mf * 512];
            __builtin_amdgcn_s_setprio(1);
            accq[mf][0] = MFMA16(aq, bf0, accq[mf][0]);
            accq[mf][1] = MFMA16(aq, bf1, accq[mf][1]);
            acck[mf][0] = MFMA16(ak, bf0, acck[mf][0]);
            acck[mf][1] = MFMA16(ak, bf1, acck[mf][1]);
            accv[mf][0] = MFMA16(av, bf0, accv[mf][0]);
            accv[mf][1] = MFMA16(av, bf1, accv[mf][1]);
            __builtin_amdgcn_s_setprio(0);
        }
    }
    __syncthreads();                   // B-tile dead; lds becomes obuf

    // qsum: column sums of delu(q)
    float qs[2] = {0.f, 0.f};
    #pragma unroll
    for (int mf = 0; mf < 4; ++mf) {
        #pragma unroll
        for (int r = 0; r < 4; ++r) {
            int o = mb * 128 + wm * 64 + mf * 16 + lk * 4 + r;
            float bqv = bq[o];
            #pragma unroll
            for (int nf = 0; nf < 2; ++nf)
                qs[nf] += delu_f(accq[mf][nf][r] + bqv);
        }
    }
    #pragma unroll
    for (int nf = 0; nf < 2; ++nf) {
        float sgl = qs[nf];
        sgl += __shfl_xor(sgl, 16);
        sgl += __shfl_xor(sgl, 32);
        if (lk == 0)
            atomicAdd(&qsum[b * Nn + n0 + wn * 32 + nf * 16 + lr], sgl);
    }

    // write k and kv into padded obuf [2][128][OSTR]
    #pragma unroll
    for (int mf = 0; mf < 4; ++mf) {
        #pragma unroll
        for (int r = 0; r < 4; ++r) {
            int ol = wm * 64 + mf * 16 + lk * 4 + r;
            float bkv = bk[mb * 128 + ol];
            float bvv = bv[mb * 128 + ol];
            #pragma unroll
            for (int nf = 0; nf < 2; ++nf) {
                float kk = delu_f(acck[mf][nf][r] + bkv);
                float vv = accv[mf][nf][r] + bvv;
                int col = wn * 32 + nf * 16 + lr;
                lds[ol * OSTR + col] = f2bf(kk);
                lds[128 * OSTR + ol * OSTR + col] = f2bf(kk * vv);
            }
        }
    }
    __syncthreads();

    // vectorized stores: per instruction, 8 rows x 128B contiguous
    #pragma unroll
    for (int i = 0; i < 4; ++i) {
        int sid = i * 256 + t;
        int o = sid >> 3, seg = sid & 7;
        short8 v = *(const short8*)&lds[o * OSTR + seg * 8];
        *(short8*)&kout[((size_t)(b * Cn + mb * 128 + o)) * Nn + n0 + seg * 8] = v;
    }
    #pragma unroll
    for (int i = 0; i < 4; ++i) {
        int sid = i * 256 + t;
        int o = sid >> 3, seg = sid & 7;
        short8 v = *(const short8*)&lds[128 * OSTR + o * OSTR + seg * 8];
        *(short8*)&kvout[((size_t)(b * Cn + mb * 128 + o)) * Nn + n0 + seg * 8] = v;
    }
}

// ---------------- esum (both pairings): esum[b,c] = sum_n k[b,c,n] * qsum[b,n] ----------------
__global__ void esum_kernel(const u16* __restrict__ k1, const u16* __restrict__ k2,
                            const float* __restrict__ qsum1, const float* __restrict__ qsum2,
                            float* __restrict__ esum1, float* __restrict__ esum2)
{
    int c = blockIdx.x, b = blockIdx.y, pair = blockIdx.z, t = threadIdx.x;
    const u16* k = pair ? k1 : k2;            // esum1 <- k2 x qsum1 ; esum2 <- k1 x qsum2
    const float* qsum = pair ? qsum2 : qsum1;
    float* esum = pair ? esum2 : esum1;
    const u16* kr = k + ((size_t)(b * Cn + c)) * Nn;
    const float* qr = qsum + b * Nn;
    float s = 0.f;
    for (int i = t * 8; i < Nn; i += 2048) {
        short8 kv = *(const short8*)&kr[i];
        #pragma unroll
        for (int j = 0; j < 8; ++j) s = fmaf(bf2f((u16)kv[j]), qr[i + j], s);
    }
    #pragma unroll
    for (int m = 32; m; m >>= 1) s += __shfl_xor(s, m);
    __shared__ float red[4];
    if ((t & 63) == 0) red[t >> 6] = s;
    __syncthreads();
    if (t == 0) esum[b * Cn + c] = red[0] + red[1] + red[2] + red[3];
}

// ---------------- norm (both pairings): 1/(sum_c esum[b,c]*k[b,c,n] + eps) ----------------
__global__ void norm_kernel(const u16* __restrict__ k1, const u16* __restrict__ k2,
                            const float* __restrict__ esum1, const float* __restrict__ esum2,
                            float* __restrict__ norm1, float* __restrict__ norm2)
{
    __shared__ float es[256];
    int t = threadIdx.x, b = blockIdx.y, pair = blockIdx.z;
    const u16* k = pair ? k1 : k2;            // norm1 <- esum1,k2 ; norm2 <- esum2,k1
    const float* esum = pair ? esum2 : esum1;
    float* nrm = pair ? norm2 : norm1;
    es[t] = esum[b * Cn + t];
    __syncthreads();
    int n = blockIdx.x * 256 + t;
    const u16* kb = k + (size_t)b * Cn * Nn + n;
    float a = 0.f;
    #pragma unroll 8
    for (int c = 0; c < 256; ++c)
        a = fmaf(es[c], bf2f(kb[(size_t)c * Nn]), a);
    nrm[b * Nn + n] = 1.f / (a + EPSn);
}

// ---------------- pass 2: merged-image slab conv, single-buffered, 2 blocks/CU ------
// block: 128 och x 512 px (4 y-rows), 8 waves. halo [6][130][32] SINGLE buffer
// (49,920 B). grid 512 = both images; XCD = (img,b). __launch_bounds__(512,2):
// VGPR cap 256 (compiler lands ~128 arch + AGPR acc) -> 2 blocks/CU from VGPR,
// LDS 2x49.9KB also fits. Cross-block overlap hides per-chunk staging drain.
#define BSZ6 (6 * 130 * 32)           // 24960 u16 per buffer

__global__ __launch_bounds__(512, 2) void conv_att_kernel(
    const u16* __restrict__ xT1, const u16* __restrict__ xT2,
    const u16* __restrict__ wallp1, const u16* __restrict__ wallp2,
    const float* __restrict__ bfused,
    const u16* __restrict__ kv1, const u16* __restrict__ kv2,
    const float* __restrict__ esum1, const float* __restrict__ esum2,
    const float* __restrict__ nrm1, const float* __restrict__ nrm2,
    const float* __restrict__ gamma1, const float* __restrict__ gamma2,
    float* __restrict__ out1, float* __restrict__ out2)
{
    __shared__ __align__(16) u16 Bl[BSZ6];   // 49,920 B single buffer
    int t = threadIdx.x;
    // 512 blocks; XCD = (img, b); slot sweeps (ys, mb) within the XCD
    int lin = (blockIdx.z * 32 + blockIdx.y) * 2 + blockIdx.x;
    int xcd = lin & 7, slot = lin >> 3;       // slot 0..63
    int img = xcd >> 2, b = xcd & 3;
    int ys = slot >> 1, mb = slot & 1;        // ys 0..31
    const u16* xT    = img ? xT2    : xT1;
    const u16* wallp = img ? wallp2 : wallp1;
    const u16* kv    = img ? kv2    : kv1;
    const float* esum = img ? esum2 : esum1;
    const float* nrm  = img ? nrm2  : nrm1;
    const float* gamma = img ? gamma2 : gamma1;
    float* out = img ? out2 : out1;

    int ybase = ys * 4;
    int lane = t & 63, wid = t >> 6;
    int wm = wid & 1, wy = wid >> 1;          // wm: och half, wy: y-row 0..3
    int lr = lane & 15, lk = lane >> 4;
    int s = mb * 2 + wm;

    f32x4 zf = {0.f, 0.f, 0.f, 0.f};
    f32x4 acc[4][8];
    #pragma unroll
    for (int i = 0; i < 4; ++i)
        #pragma unroll
        for (int j = 0; j < 8; ++j) acc[i][j] = zf;

    // zero x-pads (pos 0 and 129) for 6 rows, written once (staging never touches them)
    if (t < 48) {
        int row = t >> 3, pos = ((t >> 2) & 1) ? 129 : 0, q = t & 3;
        short8 z = {0, 0, 0, 0, 0, 0, 0, 0};
        *(short8*)&Bl[(row * 130 + pos) * 32 + q * 8] = z;
    }

    int colp = lane >> 2, chp = (lane & 3) * 8;
    auto STAGE = [&](int kc) {
        #pragma unroll
        for (int i = 0; i < 6; ++i) {
            int run = wid * 6 + i;        // 0..47 = hy(6) x seg(8)
            int hy = run >> 3, sx = run & 7;
            int yy = ybase + hy - 1;
            int dst = (hy * 130 + 1 + sx * 16) * 32;
            if (yy < 0 || yy >= Hn) {
                short8 z = {0, 0, 0, 0, 0, 0, 0, 0};
                *(short8*)&Bl[dst + lane * 8] = z;
            } else {
                const u16* g = xT + ((size_t)(b * Nn + yy * Wn + sx * 16 + colp)) * 256
                                  + kc * 32 + chp;
                GLOAD_LDS16(g, &Bl[dst]);
            }
        }
    };

    for (int kc = 0; kc < 8; ++kc) {
        int abase = ((kc * 4 + s) * 4) * 512 + lane * 8;
        // A-prefetch taps 0,1 (issued with staging; barrier drains both)
        short8 af[3][4];
        #pragma unroll
        for (int mf = 0; mf < 4; ++mf)
            af[0][mf] = *(const short8*)&wallp[0 * 65536 + abase + mf * 512];
        #pragma unroll
        for (int mf = 0; mf < 4; ++mf)
            af[1][mf] = *(const short8*)&wallp[1 * 65536 + abase + mf * 512];
        STAGE(kc);
        __syncthreads();                  // staging complete; other block hides this
        #pragma unroll
        for (int tap = 0; tap < 9; ++tap) {
            if (tap < 7) {
                #pragma unroll
                for (int mf = 0; mf < 4; ++mf)
                    af[(tap + 2) % 3][mf] =
                        *(const short8*)&wallp[(tap + 2) * 65536 + abase + mf * 512];
            }
            int dy = tap / 3, dx = tap % 3;
            short8 bf[8];
            #pragma unroll
            for (int nf = 0; nf < 8; ++nf)
                bf[nf] = *(const short8*)&Bl[((wy + dy) * 130 + nf * 16 + lr + dx) * 32 + lk * 8];
            __builtin_amdgcn_s_setprio(1);
            #pragma unroll
            for (int mf = 0; mf < 4; ++mf) {
                #pragma unroll
                for (int nf = 0; nf < 8; ++nf)
                    acc[mf][nf] = MFMA16(af[tap % 3][mf], bf[nf], acc[mf][nf]);
            }
            __builtin_amdgcn_s_setprio(0);
        }
        __syncthreads();                  // compute done before next chunk overwrites
    }

    float g = gamma[0];
    int y = ybase + wy;
    int nbase = y * Wn;
    float nr8[8];
    #pragma unroll
    for (int nf = 0; nf < 8; ++nf)
        nr8[nf] = nrm[b * Nn + nbase + nf * 16 + lr];
    #pragma unroll
    for (int mf = 0; mf < 4; ++mf) {
        #pragma unroll
        for (int r = 0; r < 4; ++r) {
            int o = mb * 128 + wm * 64 + mf * 16 + lk * 4 + r;
            float es_o = esum[b * Cn + o];
            float bf_o = bfused[o];
            size_t rowbase = ((size_t)(b * Cn + o)) * Nn + nbase;
            #pragma unroll
            for (int nf = 0; nf < 8; ++nf) {
                size_t idx = rowbase + nf * 16 + lr;
                float att = es_o * bf2f(kv[idx]) * nr8[nf];
                out[idx] = g * (acc[mf][nf][r] + bf_o + att);
            }
        }
    }
}

extern "C" void kernel_launch(void* const* d_in, const int* in_sizes, int n_in,
                              void* d_out, int out_size, void* d_ws, size_t ws_size,
                              hipStream_t stream)
{
    const float* x1  = (const float*)d_in[0];
    const float* x2  = (const float*)d_in[1];
    const float* wq1 = (const float*)d_in[2];
    const float* bq1 = (const float*)d_in[3];
    const float* wk1 = (const float*)d_in[4];
    const float* bk1 = (const float*)d_in[5];
    const float* wv1 = (const float*)d_in[6];
    const float* bv1 = (const float*)d_in[7];
    const float* wq2 = (const float*)d_in[8];
    const float* bq2 = (const float*)d_in[9];
    const float* wk2 = (const float*)d_in[10];
    const float* bk2 = (const float*)d_in[11];
    const float* wv2 = (const float*)d_in[12];
    const float* bv2 = (const float*)d_in[13];
    const float* wd1 = (const float*)d_in[14];
    const float* bd1 = (const float*)d_in[15];
    const float* wd3 = (const float*)d_in[16];
    const float* bd3 = (const float*)d_in[17];
    const float* gamma1 = (const float*)d_in[18];
    const float* gamma2 = (const float*)d_in[19];

    char* ws = (char*)d_ws;
    size_t off = 0;
    auto alloc = [&](size_t bytes) { char* p = ws + off; off += (bytes + 255) & ~(size_t)255; return p; };

    u16* xT1    = (u16*)alloc((size_t)Bn * Nn * Cn * 2);
    u16* xT2    = (u16*)alloc((size_t)Bn * Nn * Cn * 2);
    u16* k1     = (u16*)alloc((size_t)Bn * Cn * Nn * 2);
    u16* k2     = (u16*)alloc((size_t)Bn * Cn * Nn * 2);
    u16* kv2    = (u16*)alloc((size_t)Bn * Cn * Nn * 2);
    u16* wallp1 = (u16*)alloc((size_t)9 * 65536 * 2);
    u16* wallp2 = (u16*)alloc((size_t)9 * 65536 * 2);
    u16* wq1p   = (u16*)alloc(65536 * 2);
    u16* wk1p   = (u16*)alloc(65536 * 2);
    u16* wv1p   = (u16*)alloc(65536 * 2);
    u16* wq2p   = (u16*)alloc(65536 * 2);
    u16* wk2p   = (u16*)alloc(65536 * 2);
    u16* wv2p   = (u16*)alloc(65536 * 2);
    float* qsum1 = (float*)alloc(Bn * Nn * 4);
    float* qsum2 = (float*)alloc(Bn * Nn * 4);
    float* esum1 = (float*)alloc(Bn * Cn * 4);
    float* esum2 = (float*)alloc(Bn * Cn * 4);
    float* norm1 = (float*)alloc(Bn * Nn * 4);
    float* norm2 = (float*)alloc(Bn * Nn * 4);
    float* bfused = (float*)alloc(Cn * 4);
    u16* kv1    = (u16*)alloc((size_t)Bn * Cn * Nn * 2);

    float* out1 = (float*)d_out;
    float* out2 = out1 + (size_t)Bn * Cn * Nn;

    hipMemsetAsync(qsum1, 0, Bn * Nn * 4, stream);
    hipMemsetAsync(qsum2, 0, Bn * Nn * 4, stream);

    prep_kernel<<<dim3(256), dim3(256), 0, stream>>>(wq1, wk1, wv1, wq2, wk2, wv2, wd1, wd3,
                                                     bd1, bd3, gamma1, gamma2,
                                                     wq1p, wk1p, wv1p, wq2p, wk2p, wv2p,
                                                     wallp1, wallp2, bfused);
    transpose_kernel<<<dim3(256, 4, 8), 256, 0, stream>>>(x1, x2, xT1, xT2);
    qkv_kernel<<<dim3(256, 2, 8), 256, 0, stream>>>(xT1, xT2,
                                                    wq1p, wk1p, wv1p, wq2p, wk2p, wv2p,
                                                    bq1, bk1, bv1, bq2, bk2, bv2,
                                                    k1, k2, kv1, kv2, qsum1, qsum2);
    esum_kernel<<<dim3(256, 4, 2), 256, 0, stream>>>(k1, k2, qsum1, qsum2, esum1, esum2);
    norm_kernel<<<dim3(64, 4, 2), 256, 0, stream>>>(k1, k2, esum1, esum2, norm1, norm2);
    conv_att_kernel<<<dim3(2, 32, 8), 512, 0, stream>>>(xT1, xT2, wallp1, wallp2, bfused,
                                                        kv1, kv2, esum1, esum2,
                                                        norm1, norm2, gamma1, gamma2,
                                                        out1, out2);
}

// Round 17
// 328.432 us; speedup vs baseline: 8.2960x; 1.0179x over previous
//
#include <hip/hip_runtime.h>
#include <stdint.h>

#define Bn 4
#define Cn 256
#define Hn 128
#define Wn 128
#define Nn 16384
#define EPSn 1e-10f

typedef unsigned short u16;
typedef __attribute__((ext_vector_type(8))) short short8;
typedef __attribute__((ext_vector_type(4))) short short4v;
typedef __attribute__((ext_vector_type(4))) float f32x4;

#define GLOAD_LDS16(g, l)                                                        \
    __builtin_amdgcn_global_load_lds(                                            \
        (const __attribute__((address_space(1))) unsigned int*)(const void*)(g), \
        (__attribute__((address_space(3))) unsigned int*)(void*)(l), 16, 0, 0)

#define MFMA16(a, b, c) __builtin_amdgcn_mfma_f32_16x16x32_bf16(a, b, c, 0, 0, 0)

__device__ __forceinline__ float bf2f(u16 u) {
    union { float f; uint32_t i; } v; v.i = ((uint32_t)u) << 16; return v.f;
}
__device__ __forceinline__ u16 f2bf(float f) {
    union { float f; uint32_t i; } v; v.f = f;
    uint32_t r = v.i + 0x7FFFu + ((v.i >> 16) & 1u);
    return (u16)(r >> 16);
}
__device__ __forceinline__ float delu_f(float x) {
    return x >= 0.f ? fmaf(10.f, x, 1.f) : __expf(10.f * x);
}

// ---------------- prep: pack all weights into MFMA-fragment order ----------------
__global__ void prep_kernel(const float* __restrict__ wq1, const float* __restrict__ wk1,
                            const float* __restrict__ wv1,
                            const float* __restrict__ wq2, const float* __restrict__ wk2,
                            const float* __restrict__ wv2,
                            const float* __restrict__ wd1, const float* __restrict__ wd3,
                            const float* __restrict__ bd1, const float* __restrict__ bd3,
                            const float* __restrict__ gamma1, const float* __restrict__ gamma2,
                            u16* __restrict__ wq1p, u16* __restrict__ wk1p, u16* __restrict__ wv1p,
                            u16* __restrict__ wq2p, u16* __restrict__ wk2p, u16* __restrict__ wv2p,
                            u16* __restrict__ wallp1, u16* __restrict__ wallp2,
                            float* __restrict__ bfused)
{
    int idx = blockIdx.x * 256 + threadIdx.x;   // o*256 + c
    int o = idx >> 8, c = idx & 255;
    if (idx < 256) bfused[idx] = bd1[idx] + bd3[idx];
    int s = o >> 6, mf = (o >> 4) & 3, lr = o & 15;
    int kc = c >> 5, lk = (c >> 3) & 3, j = c & 7;
    int poff = ((kc * 4 + s) * 4 + mf) * 512 + (lk * 16 + lr) * 8 + j;
    wq1p[poff] = f2bf(wq1[idx]);
    wk1p[poff] = f2bf(wk1[idx]);
    wv1p[poff] = f2bf(wv1[idx]);
    wq2p[poff] = f2bf(wq2[idx]);
    wk2p[poff] = f2bf(wk2[idx]);
    wv2p[poff] = f2bf(wv2[idx]);
    float wd1v = wd1[idx];
    float inv1 = 1.f / gamma1[0];
    float inv2 = 1.f / gamma2[0];
    float diag = (o == c) ? 1.f : 0.f;
    #pragma unroll
    for (int tap = 0; tap < 9; ++tap) {
        float w = wd3[idx * 9 + tap] + (tap == 4 ? wd1v : 0.f);
        wallp1[tap * 65536 + poff] = f2bf(w + (tap == 4 ? diag * inv1 : 0.f));
        wallp2[tap * 65536 + poff] = f2bf(w + (tap == 4 ? diag * inv2 : 0.f));
    }
}

// ---------------- transpose (both images): x (B,C,N) f32 -> xT (B,N,C) bf16 ----------------
__global__ void transpose_kernel(const float* __restrict__ x1, const float* __restrict__ x2,
                                 u16* __restrict__ xT1, u16* __restrict__ xT2)
{
    __shared__ __align__(16) u16 tl[64][72];
    int t = threadIdx.x;
    int z = blockIdx.z, img = z >> 2, b = z & 3;
    const float* x = img ? x2 : x1;
    u16* xT = img ? xT2 : xT1;
    int n0 = blockIdx.x * 64, c0 = blockIdx.y * 64;
    int cl = t >> 4, nl = (t & 15) * 4;
    #pragma unroll
    for (int pc = 0; pc < 4; ++pc) {
        int c = pc * 16 + cl;
        float4 v = *(const float4*)&x[((size_t)(b * Cn + c0 + c)) * Nn + n0 + nl];
        tl[nl + 0][c] = f2bf(v.x);
        tl[nl + 1][c] = f2bf(v.y);
        tl[nl + 2][c] = f2bf(v.z);
        tl[nl + 3][c] = f2bf(v.w);
    }
    __syncthreads();
    #pragma unroll
    for (int ps = 0; ps < 2; ++ps) {
        int id = ps * 256 + t;
        int nr = id >> 3, cc = (id & 7) * 8;
        short8 v = *(const short8*)&tl[nr][cc];
        *(short8*)&xT[((size_t)(b * Nn + n0 + nr)) * 256 + c0 + cc] = v;
    }
}

// ---------------- qkv (R11 verbatim): single-shot B-tile, overlaid store bounce ----
#define OSTR 68
#define QK_LDS (2 * 128 * OSTR)        // 17408 u16 = 34816 B (Btile uses first 16384)

__global__ __launch_bounds__(256, 3) void qkv_kernel(
    const u16* __restrict__ xT1, const u16* __restrict__ xT2,
    const u16* __restrict__ wq1p, const u16* __restrict__ wk1p, const u16* __restrict__ wv1p,
    const u16* __restrict__ wq2p, const u16* __restrict__ wk2p, const u16* __restrict__ wv2p,
    const float* __restrict__ bq1, const float* __restrict__ bk1, const float* __restrict__ bv1,
    const float* __restrict__ bq2, const float* __restrict__ bk2, const float* __restrict__ bv2,
    u16* __restrict__ k1, u16* __restrict__ k2,
    u16* __restrict__ kv1, u16* __restrict__ kv2,
    float* __restrict__ qsum1, float* __restrict__ qsum2)
{
    __shared__ __align__(16) u16 lds[QK_LDS];
    int t = threadIdx.x;
    int nb = blockIdx.x, mb = blockIdx.y;
    int z = blockIdx.z, img = z >> 2, b = z & 3;
    const u16* xT  = img ? xT2  : xT1;
    const u16* wqp = img ? wq2p : wq1p;
    const u16* wkp = img ? wk2p : wk1p;
    const u16* wvp = img ? wv2p : wv1p;
    const float* bq = img ? bq2 : bq1;
    const float* bk = img ? bk2 : bk1;
    const float* bv = img ? bv2 : bv1;
    u16* kout  = img ? k2  : k1;
    u16* kvout = img ? kv2 : kv1;
    float* qsum = img ? qsum2 : qsum1;

    int n0 = nb * 64;
    int lane = t & 63, wid = t >> 6;
    int wm = wid >> 1, wn = wid & 1;
    int lr = lane & 15, lk = lane >> 4;
    int s = mb * 2 + wm;

    f32x4 zf = {0.f, 0.f, 0.f, 0.f};
    f32x4 accq[4][2], acck[4][2], accv[4][2];
    #pragma unroll
    for (int i = 0; i < 4; ++i)
        #pragma unroll
        for (int j = 0; j < 2; ++j) { accq[i][j] = zf; acck[i][j] = zf; accv[i][j] = zf; }

    int colp = lane >> 2, chp = (lane & 3) * 8;
    // stage the WHOLE B-tile: 8 loads/wave, all in flight at once
    #pragma unroll
    for (int kc = 0; kc < 8; ++kc) {
        const u16* g = xT + ((size_t)(b * Nn + n0 + wid * 16 + colp)) * 256 + kc * 32 + chp;
        GLOAD_LDS16(g, &lds[kc * 2048 + (wid * 16) * 32]);
    }
    __syncthreads();

    #pragma unroll
    for (int kc = 0; kc < 8; ++kc) {
        int abase = ((kc * 4 + s) * 4) * 512 + lane * 8;
        short8 bf0 = *(const short8*)&lds[kc * 2048 + (wn * 32 + 0 * 16 + lr) * 32 + lk * 8];
        short8 bf1 = *(const short8*)&lds[kc * 2048 + (wn * 32 + 1 * 16 + lr) * 32 + lk * 8];
        #pragma unroll
        for (int mf = 0; mf < 4; ++mf) {
            short8 aq = *(const short8*)&wqp[abase + mf * 512];
            short8 ak = *(const short8*)&wkp[abase + mf * 512];
            short8 av = *(const short8*)&wvp[abase + mf * 512];
            __builtin_amdgcn_s_setprio(1);
            accq[mf][0] = MFMA16(aq, bf0, accq[mf][0]);
            accq[mf][1] = MFMA16(aq, bf1, accq[mf][1]);
            acck[mf][0] = MFMA16(ak, bf0, acck[mf][0]);
            acck[mf][1] = MFMA16(ak, bf1, acck[mf][1]);
            accv[mf][0] = MFMA16(av, bf0, accv[mf][0]);
            accv[mf][1] = MFMA16(av, bf1, accv[mf][1]);
            __builtin_amdgcn_s_setprio(0);
        }
    }
    __syncthreads();                   // B-tile dead; lds becomes obuf

    // qsum: column sums of delu(q)
    float qs[2] = {0.f, 0.f};
    #pragma unroll
    for (int mf = 0; mf < 4; ++mf) {
        #pragma unroll
        for (int r = 0; r < 4; ++r) {
            int o = mb * 128 + wm * 64 + mf * 16 + lk * 4 + r;
            float bqv = bq[o];
            #pragma unroll
            for (int nf = 0; nf < 2; ++nf)
                qs[nf] += delu_f(accq[mf][nf][r] + bqv);
        }
    }
    #pragma unroll
    for (int nf = 0; nf < 2; ++nf) {
        float sgl = qs[nf];
        sgl += __shfl_xor(sgl, 16);
        sgl += __shfl_xor(sgl, 32);
        if (lk == 0)
            atomicAdd(&qsum[b * Nn + n0 + wn * 32 + nf * 16 + lr], sgl);
    }

    // write k and kv into padded obuf [2][128][OSTR]
    #pragma unroll
    for (int mf = 0; mf < 4; ++mf) {
        #pragma unroll
        for (int r = 0; r < 4; ++r) {
            int ol = wm * 64 + mf * 16 + lk * 4 + r;
            float bkv = bk[mb * 128 + ol];
            float bvv = bv[mb * 128 + ol];
            #pragma unroll
            for (int nf = 0; nf < 2; ++nf) {
                float kk = delu_f(acck[mf][nf][r] + bkv);
                float vv = accv[mf][nf][r] + bvv;
                int col = wn * 32 + nf * 16 + lr;
                lds[ol * OSTR + col] = f2bf(kk);
                lds[128 * OSTR + ol * OSTR + col] = f2bf(kk * vv);
            }
        }
    }
    __syncthreads();

    // vectorized stores: per instruction, 8 rows x 128B contiguous
    #pragma unroll
    for (int i = 0; i < 4; ++i) {
        int sid = i * 256 + t;
        int o = sid >> 3, seg = sid & 7;
        short8 v = *(const short8*)&lds[o * OSTR + seg * 8];
        *(short8*)&kout[((size_t)(b * Cn + mb * 128 + o)) * Nn + n0 + seg * 8] = v;
    }
    #pragma unroll
    for (int i = 0; i < 4; ++i) {
        int sid = i * 256 + t;
        int o = sid >> 3, seg = sid & 7;
        short8 v = *(const short8*)&lds[128 * OSTR + o * OSTR + seg * 8];
        *(short8*)&kvout[((size_t)(b * Cn + mb * 128 + o)) * Nn + n0 + seg * 8] = v;
    }
}

// ---------------- esum (both pairings): esum[b,c] = sum_n k[b,c,n] * qsum[b,n] ----------------
__global__ void esum_kernel(const u16* __restrict__ k1, const u16* __restrict__ k2,
                            const float* __restrict__ qsum1, const float* __restrict__ qsum2,
                            float* __restrict__ esum1, float* __restrict__ esum2)
{
    int c = blockIdx.x, b = blockIdx.y, pair = blockIdx.z, t = threadIdx.x;
    const u16* k = pair ? k1 : k2;            // esum1 <- k2 x qsum1 ; esum2 <- k1 x qsum2
    const float* qsum = pair ? qsum2 : qsum1;
    float* esum = pair ? esum2 : esum1;
    const u16* kr = k + ((size_t)(b * Cn + c)) * Nn;
    const float* qr = qsum + b * Nn;
    float s = 0.f;
    for (int i = t * 8; i < Nn; i += 2048) {
        short8 kv = *(const short8*)&kr[i];
        #pragma unroll
        for (int j = 0; j < 8; ++j) s = fmaf(bf2f((u16)kv[j]), qr[i + j], s);
    }
    #pragma unroll
    for (int m = 32; m; m >>= 1) s += __shfl_xor(s, m);
    __shared__ float red[4];
    if ((t & 63) == 0) red[t >> 6] = s;
    __syncthreads();
    if (t == 0) esum[b * Cn + c] = red[0] + red[1] + red[2] + red[3];
}

// ---------------- norm (both pairings): 1/(sum_c esum[b,c]*k[b,c,n] + eps) ----------------
__global__ void norm_kernel(const u16* __restrict__ k1, const u16* __restrict__ k2,
                            const float* __restrict__ esum1, const float* __restrict__ esum2,
                            float* __restrict__ norm1, float* __restrict__ norm2)
{
    __shared__ float es[256];
    int t = threadIdx.x, b = blockIdx.y, pair = blockIdx.z;
    const u16* k = pair ? k1 : k2;            // norm1 <- esum1,k2 ; norm2 <- esum2,k1
    const float* esum = pair ? esum2 : esum1;
    float* nrm = pair ? norm2 : norm1;
    es[t] = esum[b * Cn + t];
    __syncthreads();
    int n = blockIdx.x * 256 + t;
    const u16* kb = k + (size_t)b * Cn * Nn + n;
    float a = 0.f;
    #pragma unroll 8
    for (int c = 0; c < 256; ++c)
        a = fmaf(es[c], bf2f(kb[(size_t)c * Nn]), a);
    nrm[b * Nn + n] = 1.f / (a + EPSn);
}

// ---------------- pass 2: merged-image slab conv, DOUBLE-buffered halo ------
// block: 128 och x 512 px (4 y-rows), 8 waves. halo [6][130][32] x 2 buffers
// (99,840 B). Residency is reg-pinned at 1 block/CU (acc=128 AGPR + 128 VGPR),
// so the LDS dbuf is free and restores intra-block stage/compute overlap (R7).
#define BSZ6 (6 * 130 * 32)           // 24960 u16 per buffer

__global__ __launch_bounds__(512, 2) void conv_att_kernel(
    const u16* __restrict__ xT1, const u16* __restrict__ xT2,
    const u16* __restrict__ wallp1, const u16* __restrict__ wallp2,
    const float* __restrict__ bfused,
    const u16* __restrict__ kv1, const u16* __restrict__ kv2,
    const float* __restrict__ esum1, const float* __restrict__ esum2,
    const float* __restrict__ nrm1, const float* __restrict__ nrm2,
    const float* __restrict__ gamma1, const float* __restrict__ gamma2,
    float* __restrict__ out1, float* __restrict__ out2)
{
    __shared__ __align__(16) u16 Bl[2 * BSZ6];   // 99,840 B
    int t = threadIdx.x;
    // 512 blocks; XCD = (img, b); slot sweeps (ys, mb) within the XCD
    int lin = (blockIdx.z * 32 + blockIdx.y) * 2 + blockIdx.x;
    int xcd = lin & 7, slot = lin >> 3;       // slot 0..63
    int img = xcd >> 2, b = xcd & 3;
    int ys = slot >> 1, mb = slot & 1;        // ys 0..31
    const u16* xT    = img ? xT2    : xT1;
    const u16* wallp = img ? wallp2 : wallp1;
    const u16* kv    = img ? kv2    : kv1;
    const float* esum = img ? esum2 : esum1;
    const float* nrm  = img ? nrm2  : nrm1;
    const float* gamma = img ? gamma2 : gamma1;
    float* out = img ? out2 : out1;

    int ybase = ys * 4;
    int lane = t & 63, wid = t >> 6;
    int wm = wid & 1, wy = wid >> 1;          // wm: och half, wy: y-row 0..3
    int lr = lane & 15, lk = lane >> 4;
    int s = mb * 2 + wm;

    f32x4 zf = {0.f, 0.f, 0.f, 0.f};
    f32x4 acc[4][8];
    #pragma unroll
    for (int i = 0; i < 4; ++i)
        #pragma unroll
        for (int j = 0; j < 8; ++j) acc[i][j] = zf;

    // zero x-pads (pos 0 and 129) for 6 rows x 2 buffers, written once
    if (t < 96) {
        int buf = t / 48, r = t % 48;
        int row = r >> 3, pos = ((r >> 2) & 1) ? 129 : 0, q = r & 3;
        short8 z = {0, 0, 0, 0, 0, 0, 0, 0};
        *(short8*)&Bl[buf * BSZ6 + (row * 130 + pos) * 32 + q * 8] = z;
    }

    int colp = lane >> 2, chp = (lane & 3) * 8;
    auto STAGE = [&](int bufi, int kc) {
        #pragma unroll
        for (int i = 0; i < 6; ++i) {
            int run = wid * 6 + i;        // 0..47 = hy(6) x seg(8)
            int hy = run >> 3, sx = run & 7;
            int yy = ybase + hy - 1;
            int dst = bufi * BSZ6 + (hy * 130 + 1 + sx * 16) * 32;
            if (yy < 0 || yy >= Hn) {
                short8 z = {0, 0, 0, 0, 0, 0, 0, 0};
                *(short8*)&Bl[dst + lane * 8] = z;
            } else {
                const u16* g = xT + ((size_t)(b * Nn + yy * Wn + sx * 16 + colp)) * 256
                                  + kc * 32 + chp;
                GLOAD_LDS16(g, &Bl[dst]);
            }
        }
    };

    STAGE(0, 0);
    __syncthreads();

    for (int kc = 0; kc < 8; ++kc) {
        int cur = kc & 1;
        int abase = ((kc * 4 + s) * 4) * 512 + lane * 8;
        // A-prefetch taps 0,1 issued BEFORE next-chunk staging (in-order vmcnt retire)
        short8 af[3][4];
        #pragma unroll
        for (int mf = 0; mf < 4; ++mf)
            af[0][mf] = *(const short8*)&wallp[0 * 65536 + abase + mf * 512];
        #pragma unroll
        for (int mf = 0; mf < 4; ++mf)
            af[1][mf] = *(const short8*)&wallp[1 * 65536 + abase + mf * 512];
        if (kc < 7) STAGE(cur ^ 1, kc + 1);   // overlaps with this chunk's compute
        int cb = cur * BSZ6;
        #pragma unroll
        for (int tap = 0; tap < 9; ++tap) {
            if (tap < 7) {
                #pragma unroll
                for (int mf = 0; mf < 4; ++mf)
                    af[(tap + 2) % 3][mf] =
                        *(const short8*)&wallp[(tap + 2) * 65536 + abase + mf * 512];
            }
            int dy = tap / 3, dx = tap % 3;
            short8 bf[8];
            #pragma unroll
            for (int nf = 0; nf < 8; ++nf)
                bf[nf] = *(const short8*)&Bl[cb + ((wy + dy) * 130 + nf * 16 + lr + dx) * 32 + lk * 8];
            __builtin_amdgcn_s_setprio(1);
            #pragma unroll
            for (int mf = 0; mf < 4; ++mf) {
                #pragma unroll
                for (int nf = 0; nf < 8; ++nf)
                    acc[mf][nf] = MFMA16(af[tap % 3][mf], bf[nf], acc[mf][nf]);
            }
            __builtin_amdgcn_s_setprio(0);
        }
        __syncthreads();                  // drains staged loads + compute before swap
    }

    float g = gamma[0];
    int y = ybase + wy;
    int nbase = y * Wn;
    float nr8[8];
    #pragma unroll
    for (int nf = 0; nf < 8; ++nf)
        nr8[nf] = nrm[b * Nn + nbase + nf * 16 + lr];
    #pragma unroll
    for (int mf = 0; mf < 4; ++mf) {
        #pragma unroll
        for (int r = 0; r < 4; ++r) {
            int o = mb * 128 + wm * 64 + mf * 16 + lk * 4 + r;
            float es_o = esum[b * Cn + o];
            float bf_o = bfused[o];
            size_t rowbase = ((size_t)(b * Cn + o)) * Nn + nbase;
            #pragma unroll
            for (int nf = 0; nf < 8; ++nf) {
                size_t idx = rowbase + nf * 16 + lr;
                float att = es_o * bf2f(kv[idx]) * nr8[nf];
                out[idx] = g * (acc[mf][nf][r] + bf_o + att);
            }
        }
    }
}

extern "C" void kernel_launch(void* const* d_in, const int* in_sizes, int n_in,
                              void* d_out, int out_size, void* d_ws, size_t ws_size,
                              hipStream_t stream)
{
    const float* x1  = (const float*)d_in[0];
    const float* x2  = (const float*)d_in[1];
    const float* wq1 = (const float*)d_in[2];
    const float* bq1 = (const float*)d_in[3];
    const float* wk1 = (const float*)d_in[4];
    const float* bk1 = (const float*)d_in[5];
    const float* wv1 = (const float*)d_in[6];
    const float* bv1 = (const float*)d_in[7];
    const float* wq2 = (const float*)d_in[8];
    const float* bq2 = (const float*)d_in[9];
    const float* wk2 = (const float*)d_in[10];
    const float* bk2 = (const float*)d_in[11];
    const float* wv2 = (const float*)d_in[12];
    const float* bv2 = (const float*)d_in[13];
    const float* wd1 = (const float*)d_in[14];
    const float* bd1 = (const float*)d_in[15];
    const float* wd3 = (const float*)d_in[16];
    const float* bd3 = (const float*)d_in[17];
    const float* gamma1 = (const float*)d_in[18];
    const float* gamma2 = (const float*)d_in[19];

    char* ws = (char*)d_ws;
    size_t off = 0;
    auto alloc = [&](size_t bytes) { char* p = ws + off; off += (bytes + 255) & ~(size_t)255; return p; };

    u16* xT1    = (u16*)alloc((size_t)Bn * Nn * Cn * 2);
    u16* xT2    = (u16*)alloc((size_t)Bn * Nn * Cn * 2);
    u16* k1     = (u16*)alloc((size_t)Bn * Cn * Nn * 2);
    u16* k2     = (u16*)alloc((size_t)Bn * Cn * Nn * 2);
    u16* kv2    = (u16*)alloc((size_t)Bn * Cn * Nn * 2);
    u16* wallp1 = (u16*)alloc((size_t)9 * 65536 * 2);
    u16* wallp2 = (u16*)alloc((size_t)9 * 65536 * 2);
    u16* wq1p   = (u16*)alloc(65536 * 2);
    u16* wk1p   = (u16*)alloc(65536 * 2);
    u16* wv1p   = (u16*)alloc(65536 * 2);
    u16* wq2p   = (u16*)alloc(65536 * 2);
    u16* wk2p   = (u16*)alloc(65536 * 2);
    u16* wv2p   = (u16*)alloc(65536 * 2);
    float* qsum1 = (float*)alloc(Bn * Nn * 4);
    float* qsum2 = (float*)alloc(Bn * Nn * 4);
    float* esum1 = (float*)alloc(Bn * Cn * 4);
    float* esum2 = (float*)alloc(Bn * Cn * 4);
    float* norm1 = (float*)alloc(Bn * Nn * 4);
    float* norm2 = (float*)alloc(Bn * Nn * 4);
    float* bfused = (float*)alloc(Cn * 4);
    u16* kv1    = (u16*)alloc((size_t)Bn * Cn * Nn * 2);

    float* out1 = (float*)d_out;
    float* out2 = out1 + (size_t)Bn * Cn * Nn;

    hipMemsetAsync(qsum1, 0, Bn * Nn * 4, stream);
    hipMemsetAsync(qsum2, 0, Bn * Nn * 4, stream);

    prep_kernel<<<dim3(256), dim3(256), 0, stream>>>(wq1, wk1, wv1, wq2, wk2, wv2, wd1, wd3,
                                                     bd1, bd3, gamma1, gamma2,
                                                     wq1p, wk1p, wv1p, wq2p, wk2p, wv2p,
                                                     wallp1, wallp2, bfused);
    transpose_kernel<<<dim3(256, 4, 8), 256, 0, stream>>>(x1, x2, xT1, xT2);
    qkv_kernel<<<dim3(256, 2, 8), 256, 0, stream>>>(xT1, xT2,
                                                    wq1p, wk1p, wv1p, wq2p, wk2p, wv2p,
                                                    bq1, bk1, bv1, bq2, bk2, bv2,
                                                    k1, k2, kv1, kv2, qsum1, qsum2);
    esum_kernel<<<dim3(256, 4, 2), 256, 0, stream>>>(k1, k2, qsum1, qsum2, esum1, esum2);
    norm_kernel<<<dim3(64, 4, 2), 256, 0, stream>>>(k1, k2, esum1, esum2, norm1, norm2);
    conv_att_kernel<<<dim3(2, 32, 8), 512, 0, stream>>>(xT1, xT2, wallp1, wallp2, bfused,
                                                        kv1, kv2, esum1, esum2,
                                                        norm1, norm2, gamma1, gamma2,
                                                        out1, out2);
}

// Round 18
// 314.226 us; speedup vs baseline: 8.6711x; 1.0452x over previous
//
#include <hip/hip_runtime.h>
#include <stdint.h>

#define Bn 4
#define Cn 256
#define Hn 128
#define Wn 128
#define Nn 16384
#define EPSn 1e-10f

typedef unsigned short u16;
typedef __attribute__((ext_vector_type(8))) short short8;
typedef __attribute__((ext_vector_type(4))) short short4v;
typedef __attribute__((ext_vector_type(4))) float f32x4;

#define GLOAD_LDS16(g, l)                                                        \
    __builtin_amdgcn_global_load_lds(                                            \
        (const __attribute__((address_space(1))) unsigned int*)(const void*)(g), \
        (__attribute__((address_space(3))) unsigned int*)(void*)(l), 16, 0, 0)

#define MFMA16(a, b, c) __builtin_amdgcn_mfma_f32_16x16x32_bf16(a, b, c, 0, 0, 0)

__device__ __forceinline__ float bf2f(u16 u) {
    union { float f; uint32_t i; } v; v.i = ((uint32_t)u) << 16; return v.f;
}
__device__ __forceinline__ u16 f2bf(float f) {
    union { float f; uint32_t i; } v; v.f = f;
    uint32_t r = v.i + 0x7FFFu + ((v.i >> 16) & 1u);
    return (u16)(r >> 16);
}
__device__ __forceinline__ float delu_f(float x) {
    return x >= 0.f ? fmaf(10.f, x, 1.f) : __expf(10.f * x);
}

// ---------------- prep: pack all weights into MFMA-fragment order ----------------
__global__ void prep_kernel(const float* __restrict__ wq1, const float* __restrict__ wk1,
                            const float* __restrict__ wv1,
                            const float* __restrict__ wq2, const float* __restrict__ wk2,
                            const float* __restrict__ wv2,
                            const float* __restrict__ wd1, const float* __restrict__ wd3,
                            const float* __restrict__ bd1, const float* __restrict__ bd3,
                            const float* __restrict__ gamma1, const float* __restrict__ gamma2,
                            u16* __restrict__ wq1p, u16* __restrict__ wk1p, u16* __restrict__ wv1p,
                            u16* __restrict__ wq2p, u16* __restrict__ wk2p, u16* __restrict__ wv2p,
                            u16* __restrict__ wallp1, u16* __restrict__ wallp2,
                            float* __restrict__ bfused)
{
    int idx = blockIdx.x * 256 + threadIdx.x;   // o*256 + c
    int o = idx >> 8, c = idx & 255;
    if (idx < 256) bfused[idx] = bd1[idx] + bd3[idx];
    int s = o >> 6, mf = (o >> 4) & 3, lr = o & 15;
    int kc = c >> 5, lk = (c >> 3) & 3, j = c & 7;
    int poff = ((kc * 4 + s) * 4 + mf) * 512 + (lk * 16 + lr) * 8 + j;
    wq1p[poff] = f2bf(wq1[idx]);
    wk1p[poff] = f2bf(wk1[idx]);
    wv1p[poff] = f2bf(wv1[idx]);
    wq2p[poff] = f2bf(wq2[idx]);
    wk2p[poff] = f2bf(wk2[idx]);
    wv2p[poff] = f2bf(wv2[idx]);
    float wd1v = wd1[idx];
    float inv1 = 1.f / gamma1[0];
    float inv2 = 1.f / gamma2[0];
    float diag = (o == c) ? 1.f : 0.f;
    #pragma unroll
    for (int tap = 0; tap < 9; ++tap) {
        float w = wd3[idx * 9 + tap] + (tap == 4 ? wd1v : 0.f);
        wallp1[tap * 65536 + poff] = f2bf(w + (tap == 4 ? diag * inv1 : 0.f));
        wallp2[tap * 65536 + poff] = f2bf(w + (tap == 4 ? diag * inv2 : 0.f));
    }
}

// ---------------- transpose (both images): x (B,C,N) f32 -> xT (B,N,C) bf16 ----------------
__global__ void transpose_kernel(const float* __restrict__ x1, const float* __restrict__ x2,
                                 u16* __restrict__ xT1, u16* __restrict__ xT2)
{
    __shared__ __align__(16) u16 tl[64][72];
    int t = threadIdx.x;
    int z = blockIdx.z, img = z >> 2, b = z & 3;
    const float* x = img ? x2 : x1;
    u16* xT = img ? xT2 : xT1;
    int n0 = blockIdx.x * 64, c0 = blockIdx.y * 64;
    int cl = t >> 4, nl = (t & 15) * 4;
    #pragma unroll
    for (int pc = 0; pc < 4; ++pc) {
        int c = pc * 16 + cl;
        float4 v = *(const float4*)&x[((size_t)(b * Cn + c0 + c)) * Nn + n0 + nl];
        tl[nl + 0][c] = f2bf(v.x);
        tl[nl + 1][c] = f2bf(v.y);
        tl[nl + 2][c] = f2bf(v.z);
        tl[nl + 3][c] = f2bf(v.w);
    }
    __syncthreads();
    #pragma unroll
    for (int ps = 0; ps < 2; ++ps) {
        int id = ps * 256 + t;
        int nr = id >> 3, cc = (id & 7) * 8;
        short8 v = *(const short8*)&tl[nr][cc];
        *(short8*)&xT[((size_t)(b * Nn + n0 + nr)) * 256 + c0 + cc] = v;
    }
}

// ---------------- qkv (R11 verbatim): single-shot B-tile, overlaid store bounce ----
#define OSTR 68
#define QK_LDS (2 * 128 * OSTR)        // 17408 u16 = 34816 B (Btile uses first 16384)

__global__ __launch_bounds__(256, 3) void qkv_kernel(
    const u16* __restrict__ xT1, const u16* __restrict__ xT2,
    const u16* __restrict__ wq1p, const u16* __restrict__ wk1p, const u16* __restrict__ wv1p,
    const u16* __restrict__ wq2p, const u16* __restrict__ wk2p, const u16* __restrict__ wv2p,
    const float* __restrict__ bq1, const float* __restrict__ bk1, const float* __restrict__ bv1,
    const float* __restrict__ bq2, const float* __restrict__ bk2, const float* __restrict__ bv2,
    u16* __restrict__ k1, u16* __restrict__ k2,
    u16* __restrict__ kv1, u16* __restrict__ kv2,
    float* __restrict__ qsum1, float* __restrict__ qsum2)
{
    __shared__ __align__(16) u16 lds[QK_LDS];
    int t = threadIdx.x;
    int nb = blockIdx.x, mb = blockIdx.y;
    int z = blockIdx.z, img = z >> 2, b = z & 3;
    const u16* xT  = img ? xT2  : xT1;
    const u16* wqp = img ? wq2p : wq1p;
    const u16* wkp = img ? wk2p : wk1p;
    const u16* wvp = img ? wv2p : wv1p;
    const float* bq = img ? bq2 : bq1;
    const float* bk = img ? bk2 : bk1;
    const float* bv = img ? bv2 : bv1;
    u16* kout  = img ? k2  : k1;
    u16* kvout = img ? kv2 : kv1;
    float* qsum = img ? qsum2 : qsum1;

    int n0 = nb * 64;
    int lane = t & 63, wid = t >> 6;
    int wm = wid >> 1, wn = wid & 1;
    int lr = lane & 15, lk = lane >> 4;
    int s = mb * 2 + wm;

    f32x4 zf = {0.f, 0.f, 0.f, 0.f};
    f32x4 accq[4][2], acck[4][2], accv[4][2];
    #pragma unroll
    for (int i = 0; i < 4; ++i)
        #pragma unroll
        for (int j = 0; j < 2; ++j) { accq[i][j] = zf; acck[i][j] = zf; accv[i][j] = zf; }

    int colp = lane >> 2, chp = (lane & 3) * 8;
    // stage the WHOLE B-tile: 8 loads/wave, all in flight at once
    #pragma unroll
    for (int kc = 0; kc < 8; ++kc) {
        const u16* g = xT + ((size_t)(b * Nn + n0 + wid * 16 + colp)) * 256 + kc * 32 + chp;
        GLOAD_LDS16(g, &lds[kc * 2048 + (wid * 16) * 32]);
    }
    __syncthreads();

    #pragma unroll
    for (int kc = 0; kc < 8; ++kc) {
        int abase = ((kc * 4 + s) * 4) * 512 + lane * 8;
        short8 bf0 = *(const short8*)&lds[kc * 2048 + (wn * 32 + 0 * 16 + lr) * 32 + lk * 8];
        short8 bf1 = *(const short8*)&lds[kc * 2048 + (wn * 32 + 1 * 16 + lr) * 32 + lk * 8];
        #pragma unroll
        for (int mf = 0; mf < 4; ++mf) {
            short8 aq = *(const short8*)&wqp[abase + mf * 512];
            short8 ak = *(const short8*)&wkp[abase + mf * 512];
            short8 av = *(const short8*)&wvp[abase + mf * 512];
            __builtin_amdgcn_s_setprio(1);
            accq[mf][0] = MFMA16(aq, bf0, accq[mf][0]);
            accq[mf][1] = MFMA16(aq, bf1, accq[mf][1]);
            acck[mf][0] = MFMA16(ak, bf0, acck[mf][0]);
            acck[mf][1] = MFMA16(ak, bf1, acck[mf][1]);
            accv[mf][0] = MFMA16(av, bf0, accv[mf][0]);
            accv[mf][1] = MFMA16(av, bf1, accv[mf][1]);
            __builtin_amdgcn_s_setprio(0);
        }
    }
    __syncthreads();                   // B-tile dead; lds becomes obuf

    // qsum: column sums of delu(q)
    float qs[2] = {0.f, 0.f};
    #pragma unroll
    for (int mf = 0; mf < 4; ++mf) {
        #pragma unroll
        for (int r = 0; r < 4; ++r) {
            int o = mb * 128 + wm * 64 + mf * 16 + lk * 4 + r;
            float bqv = bq[o];
            #pragma unroll
            for (int nf = 0; nf < 2; ++nf)
                qs[nf] += delu_f(accq[mf][nf][r] + bqv);
        }
    }
    #pragma unroll
    for (int nf = 0; nf < 2; ++nf) {
        float sgl = qs[nf];
        sgl += __shfl_xor(sgl, 16);
        sgl += __shfl_xor(sgl, 32);
        if (lk == 0)
            atomicAdd(&qsum[b * Nn + n0 + wn * 32 + nf * 16 + lr], sgl);
    }

    // write k and kv into padded obuf [2][128][OSTR]
    #pragma unroll
    for (int mf = 0; mf < 4; ++mf) {
        #pragma unroll
        for (int r = 0; r < 4; ++r) {
            int ol = wm * 64 + mf * 16 + lk * 4 + r;
            float bkv = bk[mb * 128 + ol];
            float bvv = bv[mb * 128 + ol];
            #pragma unroll
            for (int nf = 0; nf < 2; ++nf) {
                float kk = delu_f(acck[mf][nf][r] + bkv);
                float vv = accv[mf][nf][r] + bvv;
                int col = wn * 32 + nf * 16 + lr;
                lds[ol * OSTR + col] = f2bf(kk);
                lds[128 * OSTR + ol * OSTR + col] = f2bf(kk * vv);
            }
        }
    }
    __syncthreads();

    // vectorized stores: per instruction, 8 rows x 128B contiguous
    #pragma unroll
    for (int i = 0; i < 4; ++i) {
        int sid = i * 256 + t;
        int o = sid >> 3, seg = sid & 7;
        short8 v = *(const short8*)&lds[o * OSTR + seg * 8];
        *(short8*)&kout[((size_t)(b * Cn + mb * 128 + o)) * Nn + n0 + seg * 8] = v;
    }
    #pragma unroll
    for (int i = 0; i < 4; ++i) {
        int sid = i * 256 + t;
        int o = sid >> 3, seg = sid & 7;
        short8 v = *(const short8*)&lds[128 * OSTR + o * OSTR + seg * 8];
        *(short8*)&kvout[((size_t)(b * Cn + mb * 128 + o)) * Nn + n0 + seg * 8] = v;
    }
}

// ---------------- esum (both pairings): esum[b,c] = sum_n k[b,c,n] * qsum[b,n] ----------------
__global__ void esum_kernel(const u16* __restrict__ k1, const u16* __restrict__ k2,
                            const float* __restrict__ qsum1, const float* __restrict__ qsum2,
                            float* __restrict__ esum1, float* __restrict__ esum2)
{
    int c = blockIdx.x, b = blockIdx.y, pair = blockIdx.z, t = threadIdx.x;
    const u16* k = pair ? k1 : k2;            // esum1 <- k2 x qsum1 ; esum2 <- k1 x qsum2
    const float* qsum = pair ? qsum2 : qsum1;
    float* esum = pair ? esum2 : esum1;
    const u16* kr = k + ((size_t)(b * Cn + c)) * Nn;
    const float* qr = qsum + b * Nn;
    float s = 0.f;
    for (int i = t * 8; i < Nn; i += 2048) {
        short8 kv = *(const short8*)&kr[i];
        #pragma unroll
        for (int j = 0; j < 8; ++j) s = fmaf(bf2f((u16)kv[j]), qr[i + j], s);
    }
    #pragma unroll
    for (int m = 32; m; m >>= 1) s += __shfl_xor(s, m);
    __shared__ float red[4];
    if ((t & 63) == 0) red[t >> 6] = s;
    __syncthreads();
    if (t == 0) esum[b * Cn + c] = red[0] + red[1] + red[2] + red[3];
}

// ---------------- norm (both pairings): 1/(sum_c esum[b,c]*k[b,c,n] + eps) ----------------
__global__ void norm_kernel(const u16* __restrict__ k1, const u16* __restrict__ k2,
                            const float* __restrict__ esum1, const float* __restrict__ esum2,
                            float* __restrict__ norm1, float* __restrict__ norm2)
{
    __shared__ float es[256];
    int t = threadIdx.x, b = blockIdx.y, pair = blockIdx.z;
    const u16* k = pair ? k1 : k2;            // norm1 <- esum1,k2 ; norm2 <- esum2,k1
    const float* esum = pair ? esum2 : esum1;
    float* nrm = pair ? norm2 : norm1;
    es[t] = esum[b * Cn + t];
    __syncthreads();
    int n = blockIdx.x * 256 + t;
    const u16* kb = k + (size_t)b * Cn * Nn + n;
    float a = 0.f;
    #pragma unroll 8
    for (int c = 0; c < 256; ++c)
        a = fmaf(es[c], bf2f(kb[(size_t)c * Nn]), a);
    nrm[b * Nn + n] = 1.f / (a + EPSn);
}

// ---------------- pass 2: merged-image conv, 4-wave blocks, 2 resident/CU ------
// block: 128 och x 2 y x 128 px, 4 waves (wm2 x wy2). halo [4][130][32] x 2 buffers
// = 66,560 B. (256,2) keeps 128 arch + 128 acc per wave -> 2 blocks/CU resident
// (regs 2x4x256 = 2048 pool; LDS 133 KB) -> cross-block desync hides af/barrier stalls.
#define BSZ4 (4 * 130 * 32)           // 16640 u16 per buffer

__global__ __launch_bounds__(256, 2) void conv_att_kernel(
    const u16* __restrict__ xT1, const u16* __restrict__ xT2,
    const u16* __restrict__ wallp1, const u16* __restrict__ wallp2,
    const float* __restrict__ bfused,
    const u16* __restrict__ kv1, const u16* __restrict__ kv2,
    const float* __restrict__ esum1, const float* __restrict__ esum2,
    const float* __restrict__ nrm1, const float* __restrict__ nrm2,
    const float* __restrict__ gamma1, const float* __restrict__ gamma2,
    float* __restrict__ out1, float* __restrict__ out2)
{
    __shared__ __align__(16) u16 Bl[2 * BSZ4];   // 66,560 B
    int t = threadIdx.x;
    // 1024 blocks; XCD = (img, b); slot sweeps (ys, mb) within the XCD
    int lin = (blockIdx.z * 64 + blockIdx.y) * 2 + blockIdx.x;
    int xcd = lin & 7, slot = lin >> 3;       // slot 0..127
    int img = xcd >> 2, b = xcd & 3;
    int ys = slot >> 1, mb = slot & 1;        // ys 0..63
    const u16* xT    = img ? xT2    : xT1;
    const u16* wallp = img ? wallp2 : wallp1;
    const u16* kv    = img ? kv2    : kv1;
    const float* esum = img ? esum2 : esum1;
    const float* nrm  = img ? nrm2  : nrm1;
    const float* gamma = img ? gamma2 : gamma1;
    float* out = img ? out2 : out1;

    int ybase = ys * 2;
    int lane = t & 63, wid = t >> 6;
    int wm = wid & 1, wy = wid >> 1;          // wm: och half, wy: y-row 0..1
    int lr = lane & 15, lk = lane >> 4;
    int s = mb * 2 + wm;

    f32x4 zf = {0.f, 0.f, 0.f, 0.f};
    f32x4 acc[4][8];
    #pragma unroll
    for (int i = 0; i < 4; ++i)
        #pragma unroll
        for (int j = 0; j < 8; ++j) acc[i][j] = zf;

    // zero x-pads (pos 0 and 129) for 4 rows x 2 buffers, written once
    if (t < 64) {
        int buf = t >> 5, r = t & 31;
        int row = r >> 3, pos = ((r >> 2) & 1) ? 129 : 0, q = r & 3;
        short8 z = {0, 0, 0, 0, 0, 0, 0, 0};
        *(short8*)&Bl[buf * BSZ4 + (row * 130 + pos) * 32 + q * 8] = z;
    }

    int colp = lane >> 2, chp = (lane & 3) * 8;
    auto STAGE = [&](int bufi, int kc) {
        #pragma unroll
        for (int i = 0; i < 8; ++i) {
            int run = wid * 8 + i;        // 0..31 = hy(4) x seg(8)
            int hy = run >> 3, sx = run & 7;
            int yy = ybase + hy - 1;
            int dst = bufi * BSZ4 + (hy * 130 + 1 + sx * 16) * 32;
            if (yy < 0 || yy >= Hn) {
                short8 z = {0, 0, 0, 0, 0, 0, 0, 0};
                *(short8*)&Bl[dst + lane * 8] = z;
            } else {
                const u16* g = xT + ((size_t)(b * Nn + yy * Wn + sx * 16 + colp)) * 256
                                  + kc * 32 + chp;
                GLOAD_LDS16(g, &Bl[dst]);
            }
        }
    };

    STAGE(0, 0);
    __syncthreads();

    for (int kc = 0; kc < 8; ++kc) {
        int cur = kc & 1;
        int abase = ((kc * 4 + s) * 4) * 512 + lane * 8;
        // A-prefetch taps 0,1 issued BEFORE next-chunk staging (in-order vmcnt retire)
        short8 af[3][4];
        #pragma unroll
        for (int mf = 0; mf < 4; ++mf)
            af[0][mf] = *(const short8*)&wallp[0 * 65536 + abase + mf * 512];
        #pragma unroll
        for (int mf = 0; mf < 4; ++mf)
            af[1][mf] = *(const short8*)&wallp[1 * 65536 + abase + mf * 512];
        if (kc < 7) STAGE(cur ^ 1, kc + 1);   // overlaps with this chunk's compute
        int cb = cur * BSZ4;
        #pragma unroll
        for (int tap = 0; tap < 9; ++tap) {
            if (tap < 7) {
                #pragma unroll
                for (int mf = 0; mf < 4; ++mf)
                    af[(tap + 2) % 3][mf] =
                        *(const short8*)&wallp[(tap + 2) * 65536 + abase + mf * 512];
            }
            int dy = tap / 3, dx = tap % 3;
            short8 bf[8];
            #pragma unroll
            for (int nf = 0; nf < 8; ++nf)
                bf[nf] = *(const short8*)&Bl[cb + ((wy + dy) * 130 + nf * 16 + lr + dx) * 32 + lk * 8];
            __builtin_amdgcn_s_setprio(1);
            #pragma unroll
            for (int mf = 0; mf < 4; ++mf) {
                #pragma unroll
                for (int nf = 0; nf < 8; ++nf)
                    acc[mf][nf] = MFMA16(af[tap % 3][mf], bf[nf], acc[mf][nf]);
            }
            __builtin_amdgcn_s_setprio(0);
        }
        __syncthreads();                  // drains staged loads + compute before swap
    }

    float g = gamma[0];
    int y = ybase + wy;
    int nbase = y * Wn;
    float nr8[8];
    #pragma unroll
    for (int nf = 0; nf < 8; ++nf)
        nr8[nf] = nrm[b * Nn + nbase + nf * 16 + lr];
    #pragma unroll
    for (int mf = 0; mf < 4; ++mf) {
        #pragma unroll
        for (int r = 0; r < 4; ++r) {
            int o = mb * 128 + wm * 64 + mf * 16 + lk * 4 + r;
            float es_o = esum[b * Cn + o];
            float bf_o = bfused[o];
            size_t rowbase = ((size_t)(b * Cn + o)) * Nn + nbase;
            #pragma unroll
            for (int nf = 0; nf < 8; ++nf) {
                size_t idx = rowbase + nf * 16 + lr;
                float att = es_o * bf2f(kv[idx]) * nr8[nf];
                out[idx] = g * (acc[mf][nf][r] + bf_o + att);
            }
        }
    }
}

extern "C" void kernel_launch(void* const* d_in, const int* in_sizes, int n_in,
                              void* d_out, int out_size, void* d_ws, size_t ws_size,
                              hipStream_t stream)
{
    const float* x1  = (const float*)d_in[0];
    const float* x2  = (const float*)d_in[1];
    const float* wq1 = (const float*)d_in[2];
    const float* bq1 = (const float*)d_in[3];
    const float* wk1 = (const float*)d_in[4];
    const float* bk1 = (const float*)d_in[5];
    const float* wv1 = (const float*)d_in[6];
    const float* bv1 = (const float*)d_in[7];
    const float* wq2 = (const float*)d_in[8];
    const float* bq2 = (const float*)d_in[9];
    const float* wk2 = (const float*)d_in[10];
    const float* bk2 = (const float*)d_in[11];
    const float* wv2 = (const float*)d_in[12];
    const float* bv2 = (const float*)d_in[13];
    const float* wd1 = (const float*)d_in[14];
    const float* bd1 = (const float*)d_in[15];
    const float* wd3 = (const float*)d_in[16];
    const float* bd3 = (const float*)d_in[17];
    const float* gamma1 = (const float*)d_in[18];
    const float* gamma2 = (const float*)d_in[19];

    char* ws = (char*)d_ws;
    size_t off = 0;
    auto alloc = [&](size_t bytes) { char* p = ws + off; off += (bytes + 255) & ~(size_t)255; return p; };

    u16* xT1    = (u16*)alloc((size_t)Bn * Nn * Cn * 2);
    u16* xT2    = (u16*)alloc((size_t)Bn * Nn * Cn * 2);
    u16* k1     = (u16*)alloc((size_t)Bn * Cn * Nn * 2);
    u16* k2     = (u16*)alloc((size_t)Bn * Cn * Nn * 2);
    u16* kv2    = (u16*)alloc((size_t)Bn * Cn * Nn * 2);
    u16* wallp1 = (u16*)alloc((size_t)9 * 65536 * 2);
    u16* wallp2 = (u16*)alloc((size_t)9 * 65536 * 2);
    u16* wq1p   = (u16*)alloc(65536 * 2);
    u16* wk1p   = (u16*)alloc(65536 * 2);
    u16* wv1p   = (u16*)alloc(65536 * 2);
    u16* wq2p   = (u16*)alloc(65536 * 2);
    u16* wk2p   = (u16*)alloc(65536 * 2);
    u16* wv2p   = (u16*)alloc(65536 * 2);
    float* qsum1 = (float*)alloc(Bn * Nn * 4);
    float* qsum2 = (float*)alloc(Bn * Nn * 4);
    float* esum1 = (float*)alloc(Bn * Cn * 4);
    float* esum2 = (float*)alloc(Bn * Cn * 4);
    float* norm1 = (float*)alloc(Bn * Nn * 4);
    float* norm2 = (float*)alloc(Bn * Nn * 4);
    float* bfused = (float*)alloc(Cn * 4);
    u16* kv1    = (u16*)alloc((size_t)Bn * Cn * Nn * 2);

    float* out1 = (float*)d_out;
    float* out2 = out1 + (size_t)Bn * Cn * Nn;

    hipMemsetAsync(qsum1, 0, Bn * Nn * 4, stream);
    hipMemsetAsync(qsum2, 0, Bn * Nn * 4, stream);

    prep_kernel<<<dim3(256), dim3(256), 0, stream>>>(wq1, wk1, wv1, wq2, wk2, wv2, wd1, wd3,
                                                     bd1, bd3, gamma1, gamma2,
                                                     wq1p, wk1p, wv1p, wq2p, wk2p, wv2p,
                                                     wallp1, wallp2, bfused);
    transpose_kernel<<<dim3(256, 4, 8), 256, 0, stream>>>(x1, x2, xT1, xT2);
    qkv_kernel<<<dim3(256, 2, 8), 256, 0, stream>>>(xT1, xT2,
                                                    wq1p, wk1p, wv1p, wq2p, wk2p, wv2p,
                                                    bq1, bk1, bv1, bq2, bk2, bv2,
                                                    k1, k2, kv1, kv2, qsum1, qsum2);
    esum_kernel<<<dim3(256, 4, 2), 256, 0, stream>>>(k1, k2, qsum1, qsum2, esum1, esum2);
    norm_kernel<<<dim3(64, 4, 2), 256, 0, stream>>>(k1, k2, esum1, esum2, norm1, norm2);
    conv_att_kernel<<<dim3(2, 64, 8), 256, 0, stream>>>(xT1, xT2, wallp1, wallp2, bfused,
                                                        kv1, kv2, esum1, esum2,
                                                        norm1, norm2, gamma1, gamma2,
                                                        out1, out2);
}